// Round 6
// baseline (3880.126 us; speedup 1.0000x reference)
//
#include <hip/hip_runtime.h>

#define IGNORE_INDEX (-100)
#define DD 2048
#define BM 256
#define BN 256
#define BK 64
#define NKT 32   // DD/BK
#define NMT 16   // 4096/BM
#define THREADS 512
#define LDS_TOTAL 139264

typedef __attribute__((ext_vector_type(8))) short bf16x8;
typedef __attribute__((ext_vector_type(4))) float f32x4;

__device__ __forceinline__ unsigned short f2bf(float f) {
    union { float f; unsigned u; } x; x.f = f;
    unsigned r = x.u + 0x7FFFu + ((x.u >> 16) & 1u);
    return (unsigned short)(r >> 16);
}

__device__ __forceinline__ void gload_lds16(const void* g, void* l) {
    __builtin_amdgcn_global_load_lds(
        (const __attribute__((address_space(1))) void*)g,
        (__attribute__((address_space(3))) void*)l, 16, 0, 0);
}

// ---------------- fp32 -> bf16 conversion (embeddings) --------------------
__global__ __launch_bounds__(256) void convE_k(const float* __restrict__ in,
                                               unsigned short* __restrict__ out,
                                               size_t nchunks) {
    size_t i = (size_t)blockIdx.x * 256 + threadIdx.x;
    if (i >= nchunks) return;
    const float4* src = (const float4*)(in + i * 8);
    float4 a = src[0], b = src[1];
    ushort4 o0 = { f2bf(a.x), f2bf(a.y), f2bf(a.z), f2bf(a.w) };
    ushort4 o1 = { f2bf(b.x), f2bf(b.y), f2bf(b.z), f2bf(b.w) };
    ushort4* dst = (ushort4*)(out + i * 8);
    dst[0] = o0; dst[1] = o1;
}

// ---------------- fp32 -> bf16 conversion (weight, zero-pad to Vpad) ------
__global__ __launch_bounds__(256) void convW_k(const float* __restrict__ wt,
                                               unsigned short* __restrict__ out,
                                               int V, size_t nchunks) {
    for (size_t i = (size_t)blockIdx.x * 256 + threadIdx.x; i < nchunks;
         i += (size_t)gridDim.x * 256) {
        size_t base = i * 8;
        size_t v = base >> 11;  // / DD
        ushort4 o0 = {0, 0, 0, 0}, o1 = {0, 0, 0, 0};
        if (v < (size_t)V) {
            const float4* src = (const float4*)(wt + base);
            float4 a = *(const float4*)&src[0];
            float4 b = *(const float4*)&src[1];
            o0 = (ushort4){ f2bf(a.x), f2bf(a.y), f2bf(a.z), f2bf(a.w) };
            o1 = (ushort4){ f2bf(b.x), f2bf(b.y), f2bf(b.z), f2bf(b.w) };
        }
        ushort4* dst = (ushort4*)(out + base);
        dst[0] = o0; dst[1] = o1;
    }
}

// ---------------- 256x256 pipelined GEMM + online-LSE epilogue ------------
// ONE barrier per region; region = {MFMA on fragments read in the PREVIOUS
// region | ds_reads for NEXT region | 1 half-tile stage}. r4 measured the
// two pipes SERIALIZED (1226 cyc/region = 620 MFMA + ~600 LDS) because all
// waves order [MFMA-burst, read-burst]. Fix: WAVE-PARITY STAGGER — group
// ((wave>>2)&1)==1 runs [reads; stage; MFMA], group 0 runs [MFMA; reads;
// stage]; the CU-shared LDS pipe serves one group while the per-SIMD matrix
// pipes serve the other, swapping mid-region. (>>2 so each SIMD under the
// id&3 mapping hosts one wave of each role.) No instruction pinning across
// the MFMA cluster (r5's SGB zip spilled: WRITE_SIZE 17->105 MB) — only one
// sched_barrier(0) between the two halves of each path.
//
// LDS map: bufA0 @0, bufB0 @32768, bufA1 @65536, bufB1 @98304 (32K each),
//          redM @131072, redS @135168. Swizzle: byte = R*128 + (cb^((R&7)<<4)).
//
// Steady-state ledger (iter i; buf0=T(2i), buf1=T(2i+1)); 2 gload_lds per
// wave per region; read-target regs disjoint from region's MFMA operands
// (checked R0..R7):
//  region | MFMA (uses regs from) | reads (for next)        | stage          | waitv
//  R0     | (0,0) aX,bP  [R7']    | c1  <- buf0.B nh1       | buf1.A.h0 2i+1 |
//  R1     | (0,1) aX,c1  [R0]     | aY  <- buf0.A mh1       | buf1.A.h1 2i+1 |
//  R2     | (1,1) aY,c1  [R1,R0]  | --                      | buf0.B.h0 2i+2 | W(2)
//  R3     | (1,0) aY,bP           | aX<-buf1.A mh0, bQ<-buf1.B nh0 | buf0.B.h1 2i+2 |
//  R4     | (0,0) aX,bQ  [R3]     | c1  <- buf1.B nh1       | buf0.A.h0 2i+2 |
//  R5     | (0,1) aX,c1  [R4]     | aY  <- buf1.A mh1       | buf0.A.h1 2i+2 |
//  R6     | (1,1) aY,c1  [R5,R4]  | --                      | buf1.B.h0 2i+3 | W(2)
//  R7     | (1,0) aY,bQ           | aX<-buf0.A mh0, bP<-buf0.B nh0 | buf1.B.h1 2i+3 |
// WAITV(2)@R2-end drains buf1 stages (prev R6/R7 + R0/R1) before the R2/R3
// barrier publishes them for R3/R5's reads; symmetric @R6-end for buf0.
// WAITV is outside the parity branch (uniform); per-wave vmcnt counts are
// identical across parities (same #loads issued per region per wave).
// Stage write-after-read: target buffer's last read-issue >=2 regions
// earlier (both parities read pre-barrier or pre-sched-fence within the
// region they're listed), published by this region's pre-barrier.

#define LDA8(DST, B, MH)                                                    \
    do {                                                                    \
        _Pragma("unroll") for (int mm = 0; mm < 4; ++mm)                    \
        _Pragma("unroll") for (int kk = 0; kk < 2; ++kk)                    \
            DST[mm][kk] = *(const bf16x8*)(smem + offA[B][kk] +             \
                                           (MH)*8192 + mm * 2048);          \
    } while (0)
#define LDB4(DST, B, NH)                                                    \
    do {                                                                    \
        _Pragma("unroll") for (int nn = 0; nn < 2; ++nn)                    \
        _Pragma("unroll") for (int kk = 0; kk < 2; ++kk)                    \
            DST[nn][kk] = *(const bf16x8*)(smem + offB[B][kk] +             \
                                           (NH)*4096 + nn * 2048);          \
    } while (0)
#define MFMAQ(MH, NH, AARR, BARR)                                           \
    do {                                                                    \
        _Pragma("unroll") for (int mm = 0; mm < 4; ++mm)                    \
        _Pragma("unroll") for (int nn = 0; nn < 2; ++nn)                    \
        _Pragma("unroll") for (int kk = 0; kk < 2; ++kk)                    \
            acc[(MH)*4 + mm][(NH)*2 + nn] =                                 \
                __builtin_amdgcn_mfma_f32_16x16x32_bf16(                    \
                    AARR[mm][kk], BARR[nn][kk],                             \
                    acc[(MH)*4 + mm][(NH)*2 + nn], 0, 0, 0);                \
    } while (0)
#define RBAR()                                                              \
    do {                                                                    \
        __builtin_amdgcn_s_barrier();                                       \
        __builtin_amdgcn_sched_barrier(0);                                  \
    } while (0)
#define WAITV(N) asm volatile("s_waitcnt vmcnt(" #N ")" ::: "memory")
#define PRIO1() __builtin_amdgcn_s_setprio(1)
#define PRIO0() __builtin_amdgcn_s_setprio(0)
#define SFENCE() __builtin_amdgcn_sched_barrier(0)

// region with wave-parity stagger; __VA_ARGS__ = loads+stage statements
#define REGION(MH, NH, AARR, BARR, ...)                                     \
    do {                                                                    \
        RBAR();                                                             \
        if (wodd) {                                                         \
            __VA_ARGS__                                                     \
            SFENCE();                                                       \
            PRIO1(); MFMAQ(MH, NH, AARR, BARR); PRIO0();                    \
        } else {                                                            \
            PRIO1(); MFMAQ(MH, NH, AARR, BARR); PRIO0();                    \
            SFENCE();                                                       \
            __VA_ARGS__                                                     \
        }                                                                   \
    } while (0)

__global__ __launch_bounds__(THREADS, 2) void gemm_lse256_k(
    const unsigned short* __restrict__ E16,   // [4096][DD] bf16 bits
    const unsigned short* __restrict__ W16,   // [Vpad][DD] bf16 bits
    const float* __restrict__ bias,           // [V]
    float2* __restrict__ partials,            // [NR][NVT]
    int NVT, int V) {
    extern __shared__ char smem[];
    const int t = threadIdx.x;
    const int lane = t & 63;
    const int wave = t >> 6;
    const int wr = wave >> 2;   // 0..1
    const int wc = wave & 3;    // 0..3
    const int lo = lane & 15;
    const int hi = lane >> 4;
    const bool wodd = ((wave >> 2) & 1) != 0;

    // bijective XCD swizzle (m204)
    const int nwg = NMT * NVT;
    const int xcd = blockIdx.x & 7;
    const int idx = blockIdx.x >> 3;
    const int q8 = nwg >> 3, r8 = nwg & 7;
    const int swz = (xcd < r8 ? xcd * (q8 + 1) : r8 * (q8 + 1) + (xcd - r8) * q8) + idx;
    const int mt = swz & (NMT - 1);
    const int vt = swz >> 4;

    const unsigned short* Ag = E16 + (size_t)mt * BM * DD;
    const unsigned short* Bg = W16 + (size_t)vt * BN * DD;

    f32x4 acc[8][4];
#pragma unroll
    for (int m = 0; m < 8; ++m)
#pragma unroll
        for (int n = 0; n < 4; ++n) acc[m][n] = (f32x4){0.f, 0.f, 0.f, 0.f};
    bf16x8 aX[4][2], aY[4][2], bP[2][2], bQ[2][2], c1[2][2];

    // ---- precomputed LDS read base offsets (loop-invariant) ----
    const int xorm = (lo & 7) << 4;
    int cbx[2];
    cbx[0] = (hi * 16) ^ xorm;
    cbx[1] = (64 + hi * 16) ^ xorm;
    int offA[2][2], offB[2][2];  // [buf][kk] byte offsets into smem
#pragma unroll
    for (int b = 0; b < 2; ++b)
#pragma unroll
        for (int k = 0; k < 2; ++k) {
            offA[b][k] = b * 65536 + (wr * 128 + lo) * 128 + cbx[k];
            offB[b][k] = 32768 + b * 65536 + (wc * 64 + lo) * 128 + cbx[k];
        }

    // ---- precomputed stage pointers (loop-invariant) ----
    const int srow = lane >> 3;
    const int cbs = ((lane & 7) * 16) ^ (srow << 4);
    const unsigned short* gA[2][2];  // [j][h]
    const unsigned short* gB[2][2];
#pragma unroll
    for (int j = 0; j < 2; ++j)
#pragma unroll
        for (int h = 0; h < 2; ++h) {
            int row = (wave * 2 + j) * 8 + srow;
            gA[j][h] = Ag + (size_t)(h * 128 + row) * DD + (cbs >> 1);
            gB[j][h] = Bg + (size_t)(h * 128 + row) * DD + (cbs >> 1);
        }
    const int wbyte = wave * 2048;

    auto stageA = [&](int b, int h, int kt) {
        int ktc = (kt & (NKT - 1)) * BK;
#pragma unroll
        for (int j = 0; j < 2; ++j)
            gload_lds16(gA[j][h] + ktc,
                        smem + b * 65536 + h * 16384 + wbyte + j * 1024);
    };
    auto stageB = [&](int b, int h, int kt) {
        int ktc = (kt & (NKT - 1)) * BK;
#pragma unroll
        for (int j = 0; j < 2; ++j)
            gload_lds16(gB[j][h] + ktc,
                        smem + 32768 + b * 65536 + h * 16384 + wbyte + j * 1024);
    };

    // prologue: T0 -> buf0 (4 halves), T1.B -> buf1 (2 halves)
    stageA(0, 0, 0); stageA(0, 1, 0);
    stageB(0, 0, 0); stageB(0, 1, 0);
    stageB(1, 0, 1); stageB(1, 1, 1);
    WAITV(4);   // T0 landed; T1.B (4 loads) in flight
    __builtin_amdgcn_s_barrier();
    __builtin_amdgcn_sched_barrier(0);
    // pre-load R0's operands from buf0
    LDA8(aX, 0, 0);
    LDB4(bP, 0, 0);

    for (int i = 0; i < NKT / 2; ++i) {
        const int k1 = 2 * i + 1, k2 = 2 * i + 2, k3 = 2 * i + 3;
        // R0
        REGION(0, 0, aX, bP, LDB4(c1, 0, 1); stageA(1, 0, k1););
        // R1
        REGION(0, 1, aX, c1, LDA8(aY, 0, 1); stageA(1, 1, k1););
        // R2
        REGION(1, 1, aY, c1, stageB(0, 0, k2););
        WAITV(2);
        // R3
        REGION(1, 0, aY, bP, LDA8(aX, 1, 0); LDB4(bQ, 1, 0); stageB(0, 1, k2););
        // R4
        REGION(0, 0, aX, bQ, LDB4(c1, 1, 1); stageA(0, 0, k2););
        // R5
        REGION(0, 1, aX, c1, LDA8(aY, 1, 1); stageA(0, 1, k2););
        // R6
        REGION(1, 1, aY, c1, stageB(1, 0, k3););
        WAITV(2);
        // R7
        REGION(1, 0, aY, bQ, LDA8(aX, 0, 0); LDB4(bP, 0, 0); stageB(1, 1, k3););
    }

    WAITV(0);
    __syncthreads();

    // ---- epilogue: bias add + per-row (max, sumexp) over this 256-col tile
    float* redM = (float*)(smem + 131072);
    float* redS = (float*)(smem + 135168);
    const int colbase = vt * BN + wc * 64 + lo;
    float bias_n[4];
#pragma unroll
    for (int n = 0; n < 4; ++n) {
        int col = colbase + n * 16;
        bias_n[n] = (col < V) ? bias[col] : 0.0f;
    }
#pragma unroll
    for (int m = 0; m < 8; ++m) {
#pragma unroll
        for (int qq = 0; qq < 4; ++qq) {
            float l[4];
            float vmax = -1e30f;
#pragma unroll
            for (int n = 0; n < 4; ++n) {
                int col = colbase + n * 16;
                float x = (col < V) ? (acc[m][n][qq] + bias_n[n]) : -1e30f;
                l[n] = x;
                vmax = fmaxf(vmax, x);
            }
#pragma unroll
            for (int d = 1; d < 16; d <<= 1) vmax = fmaxf(vmax, __shfl_xor(vmax, d));
            float s = 0.f;
#pragma unroll
            for (int n = 0; n < 4; ++n) s += __expf(l[n] - vmax);
#pragma unroll
            for (int d = 1; d < 16; d <<= 1) s += __shfl_xor(s, d);
            if (lo == 0) {
                int R = wr * 128 + m * 16 + hi * 4 + qq;
                redM[wc * 256 + R] = vmax;
                redS[wc * 256 + R] = s;
            }
        }
    }
    __syncthreads();
    if (t < 256) {
        float M = redM[t], S = redS[t];
#pragma unroll
        for (int w2 = 1; w2 < 4; ++w2) {
            float m2 = redM[w2 * 256 + t], s2 = redS[w2 * 256 + t];
            float nM = fmaxf(M, m2);
            S = S * __expf(M - nM) + s2 * __expf(m2 - nM);
            M = nM;
        }
        size_t row = (size_t)mt * BM + t;
        partials[row * (size_t)NVT + vt] = make_float2(M, S);
    }
}

// ---------------- fp32 true-logit per row (one wave per row) --------------
__global__ __launch_bounds__(256) void true_logit_k(
    const float* __restrict__ emb, const float* __restrict__ wt,
    const float* __restrict__ bias, const int* __restrict__ labels,
    float* __restrict__ tl, int* __restrict__ validf, int NR, int V, int S) {
    int wid = blockIdx.x * 4 + (threadIdx.x >> 6);
    int lane = threadIdx.x & 63;
    if (wid >= NR) return;
    int b = wid / S, s = wid % S;
    int valid = 0;
    float val = 0.f;
    if (s < S - 1) {
        int y = labels[b * S + s + 1];
        if (y != IGNORE_INDEX) {
            valid = 1;
            int ys = (y >= 0 && y < V) ? y : 0;
            const float4* e4 = (const float4*)(emb + ((size_t)b * S + s) * DD);
            const float4* w4 = (const float4*)(wt + (size_t)ys * DD);
            float sum = 0.f;
            for (int i = lane; i < DD / 4; i += 64) {
                float4 aa = e4[i], w = w4[i];
                sum += aa.x * w.x + aa.y * w.y + aa.z * w.z + aa.w * w.w;
            }
#pragma unroll
            for (int d = 1; d < 64; d <<= 1) sum += __shfl_xor(sum, d);
            val = sum + bias[ys];
        }
    }
    if (lane == 0) {
        tl[wid] = val;
        validf[wid] = valid;
    }
}

// ---------------- combine partials -> per-row NLL -> global sum -----------
__global__ __launch_bounds__(256) void reduce_rows_k(
    const float2* __restrict__ partials, const float* __restrict__ tl,
    const int* __restrict__ validf, float* __restrict__ accum, int NR,
    int NVT, int S) {
    int wid = blockIdx.x * 4 + (threadIdx.x >> 6);
    int lane = threadIdx.x & 63;
    if (wid >= NR) return;
    int s = wid % S;
    if (s >= S - 1) return;
    if (!validf[wid]) return;
    float M = -1e30f, Sm = 0.f;
    const float2* p = partials + (size_t)wid * NVT;
    for (int v = lane; v < NVT; v += 64) {
        float2 ms = p[v];
        float nM = fmaxf(M, ms.x);
        Sm = Sm * __expf(M - nM) + ms.y * __expf(ms.x - nM);
        M = nM;
    }
#pragma unroll
    for (int d = 1; d < 64; d <<= 1) {
        float oM = __shfl_xor(M, d), oS = __shfl_xor(Sm, d);
        float nM = fmaxf(M, oM);
        Sm = Sm * __expf(M - nM) + oS * __expf(oM - nM);
        M = nM;
    }
    if (lane == 0) {
        float lse = M + __logf(Sm);
        float nll = lse - tl[wid];
        atomicAdd(&accum[0], nll);
        atomicAdd(&accum[1], 1.0f);
    }
}

__global__ void finalize_k(const float* __restrict__ accum,
                           float* __restrict__ out) {
    out[0] = accum[0] / fmaxf(accum[1], 1.0f);
}

extern "C" void kernel_launch(void* const* d_in, const int* in_sizes, int n_in,
                              void* d_out, int out_size, void* d_ws,
                              size_t ws_size, hipStream_t stream) {
    const float* emb = (const float*)d_in[0];
    const float* wt = (const float*)d_in[1];
    const float* bias = (const float*)d_in[2];
    const int* labels = (const int*)d_in[3];

    const int B = 2, S = 2048;
    const int V = in_sizes[2];            // 50257
    const int NR = B * S;                 // 4096
    const int NVT = (V + BN - 1) / BN;    // 197
    const int Vpad = NVT * BN;            // 50432

    char* p = (char*)d_ws;
    unsigned short* E16 = (unsigned short*)p;
    p += (size_t)NR * DD * 2;
    float2* partials = (float2*)p;
    p += (size_t)NR * NVT * sizeof(float2);
    float* tl = (float*)p;
    p += (size_t)NR * 4;
    int* validf = (int*)p;
    p += (size_t)NR * 4;
    float* accum = (float*)p;
    p += 256;
    unsigned short* W16 = (unsigned short*)p;

    hipMemsetAsync(accum, 0, 8, stream);

    size_t echunks = (size_t)NR * DD / 8;
    convE_k<<<(int)((echunks + 255) / 256), 256, 0, stream>>>(emb, E16, echunks);

    size_t wchunks = (size_t)Vpad * DD / 8;
    convW_k<<<8192, 256, 0, stream>>>(wt, W16, V, wchunks);

    hipFuncSetAttribute((const void*)gemm_lse256_k,
                        hipFuncAttributeMaxDynamicSharedMemorySize, LDS_TOTAL);
    gemm_lse256_k<<<NMT * NVT, THREADS, LDS_TOTAL, stream>>>(E16, W16, bias,
                                                             partials, NVT, V);

    true_logit_k<<<NR / 4, 256, 0, stream>>>(emb, wt, bias, labels, tl, validf,
                                             NR, V, S);
    reduce_rows_k<<<NR / 4, 256, 0, stream>>>(partials, tl, validf, accum, NR,
                                              NVT, S);
    finalize_k<<<1, 1, 0, stream>>>(accum, (float*)d_out);
}

// Round 7
// 1152.106 us; speedup vs baseline: 3.3679x; 3.3679x over previous
//
#include <hip/hip_runtime.h>

#define IGNORE_INDEX (-100)
#define DD 2048
#define BM 256
#define BN 256
#define BK 64
#define NKT 32   // DD/BK
#define NMT 16   // 4096/BM
#define THREADS 512
#define LDS_TOTAL 139264

typedef __attribute__((ext_vector_type(8))) short bf16x8;
typedef __attribute__((ext_vector_type(4))) float f32x4;

__device__ __forceinline__ unsigned short f2bf(float f) {
    union { float f; unsigned u; } x; x.f = f;
    unsigned r = x.u + 0x7FFFu + ((x.u >> 16) & 1u);
    return (unsigned short)(r >> 16);
}

__device__ __forceinline__ void gload_lds16(const void* g, void* l) {
    __builtin_amdgcn_global_load_lds(
        (const __attribute__((address_space(1))) void*)g,
        (__attribute__((address_space(3))) void*)l, 16, 0, 0);
}

// ---------------- fp32 -> bf16 conversion (embeddings) --------------------
__global__ __launch_bounds__(256) void convE_k(const float* __restrict__ in,
                                               unsigned short* __restrict__ out,
                                               size_t nchunks) {
    size_t i = (size_t)blockIdx.x * 256 + threadIdx.x;
    if (i >= nchunks) return;
    const float4* src = (const float4*)(in + i * 8);
    float4 a = src[0], b = src[1];
    ushort4 o0 = { f2bf(a.x), f2bf(a.y), f2bf(a.z), f2bf(a.w) };
    ushort4 o1 = { f2bf(b.x), f2bf(b.y), f2bf(b.z), f2bf(b.w) };
    ushort4* dst = (ushort4*)(out + i * 8);
    dst[0] = o0; dst[1] = o1;
}

// ---------------- fp32 -> bf16 conversion (weight, zero-pad to Vpad) ------
__global__ __launch_bounds__(256) void convW_k(const float* __restrict__ wt,
                                               unsigned short* __restrict__ out,
                                               int V, size_t nchunks) {
    for (size_t i = (size_t)blockIdx.x * 256 + threadIdx.x; i < nchunks;
         i += (size_t)gridDim.x * 256) {
        size_t base = i * 8;
        size_t v = base >> 11;  // / DD
        ushort4 o0 = {0, 0, 0, 0}, o1 = {0, 0, 0, 0};
        if (v < (size_t)V) {
            const float4* src = (const float4*)(wt + base);
            float4 a = *(const float4*)&src[0];
            float4 b = *(const float4*)&src[1];
            o0 = (ushort4){ f2bf(a.x), f2bf(a.y), f2bf(a.z), f2bf(a.w) };
            o1 = (ushort4){ f2bf(b.x), f2bf(b.y), f2bf(b.z), f2bf(b.w) };
        }
        ushort4* dst = (ushort4*)(out + base);
        dst[0] = o0; dst[1] = o1;
    }
}

// ---------------- 256x256 pipelined GEMM + online-LSE epilogue ------------
// ONE barrier per region; region = {ds_reads for NEXT region; 1 half-tile
// stage; MFMA on fragments read in the PREVIOUS region} — READS ISSUED FIRST
// (uniformly, all waves). The region's reads are independent of the region's
// MFMA operands (disjoint registers, checked R0..R7), and their results are
// consumed only next region, so the compiler emits a relaxed lgkmcnt(8..12)
// before the MFMA cluster: the LDS pipe (~576 cyc/CU) processes the reads
// WHILE the matrix pipe (~620 cyc/SIMD) runs the MFMA cluster.
// r4 (MFMA-first order) measured these serialized: 1226 cyc/region.
// r5's SGB pinning and r6's parity-branch both broke regalloc (scratch
// spill, WRITE_SIZE 17->105MB / 4.5GB) — this is the no-spill version:
// no divergence, no cross-cluster pinning, same live ranges as r4.
//
// LDS map: bufA0 @0, bufB0 @32768, bufA1 @65536, bufB1 @98304 (32K each),
//          redM @131072, redS @135168. Swizzle: byte = R*128 + (cb^((R&7)<<4)).
//
// Steady-state ledger (iter i; buf0=T(2i), buf1=T(2i+1)); 2 gload_lds per
// wave per region:
//  region | MFMA (uses regs from) | reads (for next)        | stage          | waitv
//  R0     | (0,0) aX,bP  [R7']    | c1  <- buf0.B nh1       | buf1.A.h0 2i+1 |
//  R1     | (0,1) aX,c1  [R0]     | aY  <- buf0.A mh1       | buf1.A.h1 2i+1 |
//  R2     | (1,1) aY,c1  [R1,R0]  | --                      | buf0.B.h0 2i+2 | W(2)
//  R3     | (1,0) aY,bP           | aX<-buf1.A mh0, bQ<-buf1.B nh0 | buf0.B.h1 2i+2 |
//  R4     | (0,0) aX,bQ  [R3]     | c1  <- buf1.B nh1       | buf0.A.h0 2i+2 |
//  R5     | (0,1) aX,c1  [R4]     | aY  <- buf1.A mh1       | buf0.A.h1 2i+2 |
//  R6     | (1,1) aY,c1  [R5,R4]  | --                      | buf1.B.h0 2i+3 | W(2)
//  R7     | (1,0) aY,bQ           | aX<-buf0.A mh0, bP<-buf0.B nh0 | buf1.B.h1 2i+3 |
// WAITV(2)@R2-end drains buf1 stages (prev R6/R7 + R0/R1) before the R2/R3
// barrier publishes them for R3/R5's reads; symmetric @R6-end for buf0.
// Per-region per-wave issue counts are order-invariant, so vmcnt ledger is
// identical to r4. Stage write-after-read: the staged buffer's last reads
// were issued in an earlier region (barrier-separated); moving reads to
// region start only WIDENS the read-execute vs stage-write-land gap.

#define LDA8(DST, B, MH)                                                    \
    do {                                                                    \
        _Pragma("unroll") for (int mm = 0; mm < 4; ++mm)                    \
        _Pragma("unroll") for (int kk = 0; kk < 2; ++kk)                    \
            DST[mm][kk] = *(const bf16x8*)(smem + offA[B][kk] +             \
                                           (MH)*8192 + mm * 2048);          \
    } while (0)
#define LDB4(DST, B, NH)                                                    \
    do {                                                                    \
        _Pragma("unroll") for (int nn = 0; nn < 2; ++nn)                    \
        _Pragma("unroll") for (int kk = 0; kk < 2; ++kk)                    \
            DST[nn][kk] = *(const bf16x8*)(smem + offB[B][kk] +             \
                                           (NH)*4096 + nn * 2048);          \
    } while (0)
#define MFMAQ(MH, NH, AARR, BARR)                                           \
    do {                                                                    \
        __builtin_amdgcn_s_setprio(1);                                      \
        _Pragma("unroll") for (int mm = 0; mm < 4; ++mm)                    \
        _Pragma("unroll") for (int nn = 0; nn < 2; ++nn)                    \
        _Pragma("unroll") for (int kk = 0; kk < 2; ++kk)                    \
            acc[(MH)*4 + mm][(NH)*2 + nn] =                                 \
                __builtin_amdgcn_mfma_f32_16x16x32_bf16(                    \
                    AARR[mm][kk], BARR[nn][kk],                             \
                    acc[(MH)*4 + mm][(NH)*2 + nn], 0, 0, 0);                \
        __builtin_amdgcn_s_setprio(0);                                      \
    } while (0)
#define RBAR()                                                              \
    do {                                                                    \
        __builtin_amdgcn_s_barrier();                                       \
        __builtin_amdgcn_sched_barrier(0);                                  \
    } while (0)
#define WAITV(N) asm volatile("s_waitcnt vmcnt(" #N ")" ::: "memory")

__global__ __launch_bounds__(THREADS, 2) void gemm_lse256_k(
    const unsigned short* __restrict__ E16,   // [4096][DD] bf16 bits
    const unsigned short* __restrict__ W16,   // [Vpad][DD] bf16 bits
    const float* __restrict__ bias,           // [V]
    float2* __restrict__ partials,            // [NR][NVT]
    int NVT, int V) {
    extern __shared__ char smem[];
    const int t = threadIdx.x;
    const int lane = t & 63;
    const int wave = t >> 6;
    const int wr = wave >> 2;   // 0..1
    const int wc = wave & 3;    // 0..3
    const int lo = lane & 15;
    const int hi = lane >> 4;

    // bijective XCD swizzle (m204)
    const int nwg = NMT * NVT;
    const int xcd = blockIdx.x & 7;
    const int idx = blockIdx.x >> 3;
    const int q8 = nwg >> 3, r8 = nwg & 7;
    const int swz = (xcd < r8 ? xcd * (q8 + 1) : r8 * (q8 + 1) + (xcd - r8) * q8) + idx;
    const int mt = swz & (NMT - 1);
    const int vt = swz >> 4;

    const unsigned short* Ag = E16 + (size_t)mt * BM * DD;
    const unsigned short* Bg = W16 + (size_t)vt * BN * DD;

    f32x4 acc[8][4];
#pragma unroll
    for (int m = 0; m < 8; ++m)
#pragma unroll
        for (int n = 0; n < 4; ++n) acc[m][n] = (f32x4){0.f, 0.f, 0.f, 0.f};
    bf16x8 aX[4][2], aY[4][2], bP[2][2], bQ[2][2], c1[2][2];

    // ---- precomputed LDS read base offsets (loop-invariant) ----
    const int xorm = (lo & 7) << 4;
    int cbx[2];
    cbx[0] = (hi * 16) ^ xorm;
    cbx[1] = (64 + hi * 16) ^ xorm;
    int offA[2][2], offB[2][2];  // [buf][kk] byte offsets into smem
#pragma unroll
    for (int b = 0; b < 2; ++b)
#pragma unroll
        for (int k = 0; k < 2; ++k) {
            offA[b][k] = b * 65536 + (wr * 128 + lo) * 128 + cbx[k];
            offB[b][k] = 32768 + b * 65536 + (wc * 64 + lo) * 128 + cbx[k];
        }

    // ---- precomputed stage pointers (loop-invariant) ----
    const int srow = lane >> 3;
    const int cbs = ((lane & 7) * 16) ^ (srow << 4);
    const unsigned short* gA[2][2];  // [j][h]
    const unsigned short* gB[2][2];
#pragma unroll
    for (int j = 0; j < 2; ++j)
#pragma unroll
        for (int h = 0; h < 2; ++h) {
            int row = (wave * 2 + j) * 8 + srow;
            gA[j][h] = Ag + (size_t)(h * 128 + row) * DD + (cbs >> 1);
            gB[j][h] = Bg + (size_t)(h * 128 + row) * DD + (cbs >> 1);
        }
    const int wbyte = wave * 2048;

    auto stageA = [&](int b, int h, int kt) {
        int ktc = (kt & (NKT - 1)) * BK;
#pragma unroll
        for (int j = 0; j < 2; ++j)
            gload_lds16(gA[j][h] + ktc,
                        smem + b * 65536 + h * 16384 + wbyte + j * 1024);
    };
    auto stageB = [&](int b, int h, int kt) {
        int ktc = (kt & (NKT - 1)) * BK;
#pragma unroll
        for (int j = 0; j < 2; ++j)
            gload_lds16(gB[j][h] + ktc,
                        smem + 32768 + b * 65536 + h * 16384 + wbyte + j * 1024);
    };

    // prologue: T0 -> buf0 (4 halves), T1.B -> buf1 (2 halves)
    stageA(0, 0, 0); stageA(0, 1, 0);
    stageB(0, 0, 0); stageB(0, 1, 0);
    stageB(1, 0, 1); stageB(1, 1, 1);
    WAITV(4);   // T0 landed; T1.B (4 loads) in flight
    __builtin_amdgcn_s_barrier();
    __builtin_amdgcn_sched_barrier(0);
    // pre-load R0's operands from buf0
    LDA8(aX, 0, 0);
    LDB4(bP, 0, 0);

    for (int i = 0; i < NKT / 2; ++i) {
        const int k1 = 2 * i + 1, k2 = 2 * i + 2, k3 = 2 * i + 3;
        // R0: reads first, then MFMA (overlap in pipes)
        RBAR();
        LDB4(c1, 0, 1);
        stageA(1, 0, k1);
        MFMAQ(0, 0, aX, bP);
        // R1
        RBAR();
        LDA8(aY, 0, 1);
        stageA(1, 1, k1);
        MFMAQ(0, 1, aX, c1);
        // R2
        RBAR();
        stageB(0, 0, k2);
        MFMAQ(1, 1, aY, c1);
        WAITV(2);
        // R3
        RBAR();
        LDA8(aX, 1, 0);
        LDB4(bQ, 1, 0);
        stageB(0, 1, k2);
        MFMAQ(1, 0, aY, bP);
        // R4
        RBAR();
        LDB4(c1, 1, 1);
        stageA(0, 0, k2);
        MFMAQ(0, 0, aX, bQ);
        // R5
        RBAR();
        LDA8(aY, 1, 1);
        stageA(0, 1, k2);
        MFMAQ(0, 1, aX, c1);
        // R6
        RBAR();
        stageB(1, 0, k3);
        MFMAQ(1, 1, aY, c1);
        WAITV(2);
        // R7
        RBAR();
        LDA8(aX, 0, 0);
        LDB4(bP, 0, 0);
        stageB(1, 1, k3);
        MFMAQ(1, 0, aY, bQ);
    }

    WAITV(0);
    __syncthreads();

    // ---- epilogue: bias add + per-row (max, sumexp) over this 256-col tile
    float* redM = (float*)(smem + 131072);
    float* redS = (float*)(smem + 135168);
    const int colbase = vt * BN + wc * 64 + lo;
    float bias_n[4];
#pragma unroll
    for (int n = 0; n < 4; ++n) {
        int col = colbase + n * 16;
        bias_n[n] = (col < V) ? bias[col] : 0.0f;
    }
#pragma unroll
    for (int m = 0; m < 8; ++m) {
#pragma unroll
        for (int qq = 0; qq < 4; ++qq) {
            float l[4];
            float vmax = -1e30f;
#pragma unroll
            for (int n = 0; n < 4; ++n) {
                int col = colbase + n * 16;
                float x = (col < V) ? (acc[m][n][qq] + bias_n[n]) : -1e30f;
                l[n] = x;
                vmax = fmaxf(vmax, x);
            }
#pragma unroll
            for (int d = 1; d < 16; d <<= 1) vmax = fmaxf(vmax, __shfl_xor(vmax, d));
            float s = 0.f;
#pragma unroll
            for (int n = 0; n < 4; ++n) s += __expf(l[n] - vmax);
#pragma unroll
            for (int d = 1; d < 16; d <<= 1) s += __shfl_xor(s, d);
            if (lo == 0) {
                int R = wr * 128 + m * 16 + hi * 4 + qq;
                redM[wc * 256 + R] = vmax;
                redS[wc * 256 + R] = s;
            }
        }
    }
    __syncthreads();
    if (t < 256) {
        float M = redM[t], S = redS[t];
#pragma unroll
        for (int w2 = 1; w2 < 4; ++w2) {
            float m2 = redM[w2 * 256 + t], s2 = redS[w2 * 256 + t];
            float nM = fmaxf(M, m2);
            S = S * __expf(M - nM) + s2 * __expf(m2 - nM);
            M = nM;
        }
        size_t row = (size_t)mt * BM + t;
        partials[row * (size_t)NVT + vt] = make_float2(M, S);
    }
}

// ---------------- fp32 true-logit per row (one wave per row) --------------
__global__ __launch_bounds__(256) void true_logit_k(
    const float* __restrict__ emb, const float* __restrict__ wt,
    const float* __restrict__ bias, const int* __restrict__ labels,
    float* __restrict__ tl, int* __restrict__ validf, int NR, int V, int S) {
    int wid = blockIdx.x * 4 + (threadIdx.x >> 6);
    int lane = threadIdx.x & 63;
    if (wid >= NR) return;
    int b = wid / S, s = wid % S;
    int valid = 0;
    float val = 0.f;
    if (s < S - 1) {
        int y = labels[b * S + s + 1];
        if (y != IGNORE_INDEX) {
            valid = 1;
            int ys = (y >= 0 && y < V) ? y : 0;
            const float4* e4 = (const float4*)(emb + ((size_t)b * S + s) * DD);
            const float4* w4 = (const float4*)(wt + (size_t)ys * DD);
            float sum = 0.f;
            for (int i = lane; i < DD / 4; i += 64) {
                float4 aa = e4[i], w = w4[i];
                sum += aa.x * w.x + aa.y * w.y + aa.z * w.z + aa.w * w.w;
            }
#pragma unroll
            for (int d = 1; d < 64; d <<= 1) sum += __shfl_xor(sum, d);
            val = sum + bias[ys];
        }
    }
    if (lane == 0) {
        tl[wid] = val;
        validf[wid] = valid;
    }
}

// ---------------- combine partials -> per-row NLL -> global sum -----------
__global__ __launch_bounds__(256) void reduce_rows_k(
    const float2* __restrict__ partials, const float* __restrict__ tl,
    const int* __restrict__ validf, float* __restrict__ accum, int NR,
    int NVT, int S) {
    int wid = blockIdx.x * 4 + (threadIdx.x >> 6);
    int lane = threadIdx.x & 63;
    if (wid >= NR) return;
    int s = wid % S;
    if (s >= S - 1) return;
    if (!validf[wid]) return;
    float M = -1e30f, Sm = 0.f;
    const float2* p = partials + (size_t)wid * NVT;
    for (int v = lane; v < NVT; v += 64) {
        float2 ms = p[v];
        float nM = fmaxf(M, ms.x);
        Sm = Sm * __expf(M - nM) + ms.y * __expf(ms.x - nM);
        M = nM;
    }
#pragma unroll
    for (int d = 1; d < 64; d <<= 1) {
        float oM = __shfl_xor(M, d), oS = __shfl_xor(Sm, d);
        float nM = fmaxf(M, oM);
        Sm = Sm * __expf(M - nM) + oS * __expf(oM - nM);
        M = nM;
    }
    if (lane == 0) {
        float lse = M + __logf(Sm);
        float nll = lse - tl[wid];
        atomicAdd(&accum[0], nll);
        atomicAdd(&accum[1], 1.0f);
    }
}

__global__ void finalize_k(const float* __restrict__ accum,
                           float* __restrict__ out) {
    out[0] = accum[0] / fmaxf(accum[1], 1.0f);
}

extern "C" void kernel_launch(void* const* d_in, const int* in_sizes, int n_in,
                              void* d_out, int out_size, void* d_ws,
                              size_t ws_size, hipStream_t stream) {
    const float* emb = (const float*)d_in[0];
    const float* wt = (const float*)d_in[1];
    const float* bias = (const float*)d_in[2];
    const int* labels = (const int*)d_in[3];

    const int B = 2, S = 2048;
    const int V = in_sizes[2];            // 50257
    const int NR = B * S;                 // 4096
    const int NVT = (V + BN - 1) / BN;    // 197
    const int Vpad = NVT * BN;            // 50432

    char* p = (char*)d_ws;
    unsigned short* E16 = (unsigned short*)p;
    p += (size_t)NR * DD * 2;
    float2* partials = (float2*)p;
    p += (size_t)NR * NVT * sizeof(float2);
    float* tl = (float*)p;
    p += (size_t)NR * 4;
    int* validf = (int*)p;
    p += (size_t)NR * 4;
    float* accum = (float*)p;
    p += 256;
    unsigned short* W16 = (unsigned short*)p;

    hipMemsetAsync(accum, 0, 8, stream);

    size_t echunks = (size_t)NR * DD / 8;
    convE_k<<<(int)((echunks + 255) / 256), 256, 0, stream>>>(emb, E16, echunks);

    size_t wchunks = (size_t)Vpad * DD / 8;
    convW_k<<<8192, 256, 0, stream>>>(wt, W16, V, wchunks);

    hipFuncSetAttribute((const void*)gemm_lse256_k,
                        hipFuncAttributeMaxDynamicSharedMemorySize, LDS_TOTAL);
    gemm_lse256_k<<<NMT * NVT, THREADS, LDS_TOTAL, stream>>>(E16, W16, bias,
                                                             partials, NVT, V);

    true_logit_k<<<NR / 4, 256, 0, stream>>>(emb, wt, bias, labels, tl, validf,
                                             NR, V, S);
    reduce_rows_k<<<NR / 4, 256, 0, stream>>>(partials, tl, validf, accum, NR,
                                              NVT, S);
    finalize_k<<<1, 1, 0, stream>>>(accum, (float*)d_out);
}

// Round 8
// 832.318 us; speedup vs baseline: 4.6618x; 1.3842x over previous
//
#include <hip/hip_runtime.h>

#define IGNORE_INDEX (-100)
#define DD 2048
#define BM 256
#define BN 256
#define BKB 128   // K-tile in BYTES = 128 fp8 elements
#define NKT 16    // DD/128
#define NMT 16    // 4096/BM
#define THREADS 512
#define LDS_TOTAL 139264

typedef __attribute__((ext_vector_type(4))) float f32x4;
typedef __attribute__((ext_vector_type(2))) long lx2;

// ---- fp32 -> fp8 e4m3 (OCP) pair-pack via HW converter -------------------
__device__ __forceinline__ unsigned cvt8x4(float a, float b, float c, float d) {
    unsigned r = 0;
    r = __builtin_amdgcn_cvt_pk_fp8_f32(a, b, r, false);  // bytes 0-1
    r = __builtin_amdgcn_cvt_pk_fp8_f32(c, d, r, true);   // bytes 2-3
    return r;
}

__device__ __forceinline__ void gload_lds16(const void* g, void* l) {
    __builtin_amdgcn_global_load_lds(
        (const __attribute__((address_space(1))) void*)g,
        (__attribute__((address_space(3))) void*)l, 16, 0, 0);
}

// Permuted fp8 layout: within each 128-B k-tile, byte c holds element
// k(c) = ((c>>6)&1)*64 + ((c>>3)&1)*32 + ((c>>4)&3)*8 + (c&7)   [bijective]
// so a b128 read at col r*64+hi*16 yields bytes off=0..15 -> elements
// k = r*64 + (off>>3)*32 + hi*8 + (off&7): first 8B = k-step 2r, lane-k
// hi*8..hi*8+7; second 8B = k-step 2r+1. One read = two i64 MFMA fragments.
// For 8-aligned output byte c (c&7==0), k(c)..k(c)+7 are 8 CONSECUTIVE
// input elements starting at kbase(c) = ((c>>6)&1)*64+((c>>3)&1)*32+((c>>4)&3)*8.

// ---------------- fp32 -> fp8 conversion (embeddings, permuted) -----------
__global__ __launch_bounds__(256) void convE8_k(const float* __restrict__ in,
                                                unsigned char* __restrict__ out,
                                                size_t nchunks) {
    size_t i = (size_t)blockIdx.x * 256 + threadIdx.x;
    if (i >= nchunks) return;
    size_t o = i * 8;                       // output byte base (8-aligned)
    size_t rowbase = o & ~(size_t)2047;     // row*2048 + ktile base
    unsigned c = (unsigned)o & 127;
    unsigned kb = ((c >> 6) & 1) * 64 + ((c >> 3) & 1) * 32 + ((c >> 4) & 3) * 8;
    const float* src = in + rowbase + (o & 2047 & ~127u) + kb;
    float4 a = *(const float4*)src;
    float4 b = *(const float4*)(src + 4);
    uint2 v = { cvt8x4(a.x, a.y, a.z, a.w), cvt8x4(b.x, b.y, b.z, b.w) };
    *(uint2*)(out + o) = v;
}

// ---------------- fp32 -> fp8 conversion (weight, permuted, zero-pad) -----
__global__ __launch_bounds__(256) void convW8_k(const float* __restrict__ wt,
                                                unsigned char* __restrict__ out,
                                                int V, size_t nchunks) {
    for (size_t i = (size_t)blockIdx.x * 256 + threadIdx.x; i < nchunks;
         i += (size_t)gridDim.x * 256) {
        size_t o = i * 8;
        size_t v = o >> 11;
        uint2 val = {0u, 0u};
        if (v < (size_t)V) {
            unsigned c = (unsigned)o & 127;
            unsigned kb = ((c >> 6) & 1) * 64 + ((c >> 3) & 1) * 32 + ((c >> 4) & 3) * 8;
            const float* src = wt + (o & ~(size_t)2047) + (o & 2047 & ~127u) + kb;
            float4 a = *(const float4*)src;
            float4 b = *(const float4*)(src + 4);
            val = (uint2){ cvt8x4(a.x, a.y, a.z, a.w), cvt8x4(b.x, b.y, b.z, b.w) };
        }
        *(uint2*)(out + o) = val;
    }
}

// ---------------- 256x256 fp8 pipelined GEMM + online-LSE epilogue --------
// r4's proven one-barrier region schedule (804us bf16), operands switched to
// fp8-e4m3: SAME byte geometry (256-row x 128-B LDS tiles, same XOR swizzle,
// same stage pattern, same vmcnt ledger), but each 128-B row now covers
// K=128 elements (vs 64), so each region runs 32 MFMA/wave (vs 16) on the
// SAME ds_read instruction count -> LDS-side cost per MFMA-cycle halves.
// NKT=16, 8 iters of 8 regions. Fragment regs: a[4][4] i64 = 32 VGPR (same
// as bf16's a[4][2] bf16x8); no new live ranges vs r4 -> no spill expected.
//
// LDS map: bufA0 @0, bufB0 @32768, bufA1 @65536, bufB1 @98304 (32K each),
//          redM @131072, redS @135168. Swizzle: byte = R*128 + (cb^((R&7)<<4)).
// Ledger (iter i; buf0=T(2i), buf1=T(2i+1)); 2 gload_lds/wave/region:
//  region | MFMA quadrant (regs from) | reads (for next)     | stage          | waitv
//  R0     | (0,0) aX,bP  [R7']    | c1  <- buf0.B nh1        | buf1.A.h0 2i+1 |
//  R1     | (0,1) aX,c1  [R0]     | aY  <- buf0.A mh1        | buf1.A.h1 2i+1 |
//  R2     | (1,1) aY,c1  [R1,R0]  | --                       | buf0.B.h0 2i+2 | W(2)
//  R3     | (1,0) aY,bP           | aX<-buf1.A mh0, bQ<-buf1.B nh0 | buf0.B.h1 2i+2 |
//  R4     | (0,0) aX,bQ  [R3]     | c1  <- buf1.B nh1        | buf0.A.h0 2i+2 |
//  R5     | (0,1) aX,c1  [R4]     | aY  <- buf1.A mh1        | buf0.A.h1 2i+2 |
//  R6     | (1,1) aY,c1  [R5,R4]  | --                       | buf1.B.h0 2i+3 | W(2)
//  R7     | (1,0) aY,bQ           | aX<-buf0.A mh0, bP<-buf0.B nh0 | buf1.B.h1 2i+3 |

#define LDA8(DST, B, MH)                                                    \
    do {                                                                    \
        _Pragma("unroll") for (int mm = 0; mm < 4; ++mm)                    \
        _Pragma("unroll") for (int rr = 0; rr < 2; ++rr) {                  \
            lx2 v = *(const lx2*)(smem + offA[B][rr] + (MH)*8192 +          \
                                  mm * 2048);                               \
            DST[mm][2 * rr] = v.x;                                          \
            DST[mm][2 * rr + 1] = v.y;                                      \
        }                                                                   \
    } while (0)
#define LDB4(DST, B, NH)                                                    \
    do {                                                                    \
        _Pragma("unroll") for (int nn = 0; nn < 2; ++nn)                    \
        _Pragma("unroll") for (int rr = 0; rr < 2; ++rr) {                  \
            lx2 v = *(const lx2*)(smem + offB[B][rr] + (NH)*4096 +          \
                                  nn * 2048);                               \
            DST[nn][2 * rr] = v.x;                                          \
            DST[nn][2 * rr + 1] = v.y;                                      \
        }                                                                   \
    } while (0)
#define MFMAQ(MH, NH, AARR, BARR)                                           \
    do {                                                                    \
        __builtin_amdgcn_s_setprio(1);                                      \
        _Pragma("unroll") for (int mm = 0; mm < 4; ++mm)                    \
        _Pragma("unroll") for (int nn = 0; nn < 2; ++nn)                    \
        _Pragma("unroll") for (int ss = 0; ss < 4; ++ss)                    \
            acc[(MH)*4 + mm][(NH)*2 + nn] =                                 \
                __builtin_amdgcn_mfma_f32_16x16x32_fp8_fp8(                 \
                    AARR[mm][ss], BARR[nn][ss],                             \
                    acc[(MH)*4 + mm][(NH)*2 + nn], 0, 0, 0);                \
        __builtin_amdgcn_s_setprio(0);                                      \
    } while (0)
#define RBAR()                                                              \
    do {                                                                    \
        __builtin_amdgcn_s_barrier();                                       \
        __builtin_amdgcn_sched_barrier(0);                                  \
    } while (0)
#define WAITV(N) asm volatile("s_waitcnt vmcnt(" #N ")" ::: "memory")

__global__ __launch_bounds__(THREADS, 2) void gemm_lse256_k(
    const unsigned char* __restrict__ E8,    // [4096][2048 B] permuted fp8
    const unsigned char* __restrict__ W8,    // [Vpad][2048 B] permuted fp8
    const float* __restrict__ bias,          // [V]
    float2* __restrict__ partials,           // [NR][NVT]
    int NVT, int V) {
    extern __shared__ char smem[];
    const int t = threadIdx.x;
    const int lane = t & 63;
    const int wave = t >> 6;
    const int wr = wave >> 2;   // 0..1
    const int wc = wave & 3;    // 0..3
    const int lo = lane & 15;
    const int hi = lane >> 4;

    // bijective XCD swizzle (m204)
    const int nwg = NMT * NVT;
    const int xcd = blockIdx.x & 7;
    const int idx = blockIdx.x >> 3;
    const int q8 = nwg >> 3, r8 = nwg & 7;
    const int swz = (xcd < r8 ? xcd * (q8 + 1) : r8 * (q8 + 1) + (xcd - r8) * q8) + idx;
    const int mt = swz & (NMT - 1);
    const int vt = swz >> 4;

    const unsigned char* Ag = E8 + (size_t)mt * BM * DD;
    const unsigned char* Bg = W8 + (size_t)vt * BN * DD;

    f32x4 acc[8][4];
#pragma unroll
    for (int m = 0; m < 8; ++m)
#pragma unroll
        for (int n = 0; n < 4; ++n) acc[m][n] = (f32x4){0.f, 0.f, 0.f, 0.f};
    long aX[4][4], aY[4][4], bP[2][4], bQ[2][4], c1[2][4];

    // ---- precomputed LDS read base offsets (loop-invariant) ----
    const int xorm = (lo & 7) << 4;
    int cbx[2];
    cbx[0] = (hi * 16) ^ xorm;
    cbx[1] = (64 + hi * 16) ^ xorm;
    int offA[2][2], offB[2][2];  // [buf][rr] byte offsets into smem
#pragma unroll
    for (int b = 0; b < 2; ++b)
#pragma unroll
        for (int k = 0; k < 2; ++k) {
            offA[b][k] = b * 65536 + (wr * 128 + lo) * 128 + cbx[k];
            offB[b][k] = 32768 + b * 65536 + (wc * 64 + lo) * 128 + cbx[k];
        }

    // ---- precomputed stage pointers (loop-invariant) ----
    const int srow = lane >> 3;
    const int cbs = ((lane & 7) * 16) ^ (srow << 4);
    const unsigned char* gA[2][2];  // [j][h]
    const unsigned char* gB[2][2];
#pragma unroll
    for (int j = 0; j < 2; ++j)
#pragma unroll
        for (int h = 0; h < 2; ++h) {
            int row = (wave * 2 + j) * 8 + srow;
            gA[j][h] = Ag + (size_t)(h * 128 + row) * DD + cbs;
            gB[j][h] = Bg + (size_t)(h * 128 + row) * DD + cbs;
        }
    const int wbyte = wave * 2048;

    auto stageA = [&](int b, int h, int kt) {
        int ktc = (kt & (NKT - 1)) * BKB;
#pragma unroll
        for (int j = 0; j < 2; ++j)
            gload_lds16(gA[j][h] + ktc,
                        smem + b * 65536 + h * 16384 + wbyte + j * 1024);
    };
    auto stageB = [&](int b, int h, int kt) {
        int ktc = (kt & (NKT - 1)) * BKB;
#pragma unroll
        for (int j = 0; j < 2; ++j)
            gload_lds16(gB[j][h] + ktc,
                        smem + 32768 + b * 65536 + h * 16384 + wbyte + j * 1024);
    };

    // prologue: T0 -> buf0 (4 halves), T1.B -> buf1 (2 halves)
    stageA(0, 0, 0); stageA(0, 1, 0);
    stageB(0, 0, 0); stageB(0, 1, 0);
    stageB(1, 0, 1); stageB(1, 1, 1);
    WAITV(4);   // T0 landed; T1.B (4 loads) in flight
    __builtin_amdgcn_s_barrier();
    __builtin_amdgcn_sched_barrier(0);
    // pre-load R0's operands from buf0
    LDA8(aX, 0, 0);
    LDB4(bP, 0, 0);

    for (int i = 0; i < NKT / 2; ++i) {
        const int k1 = 2 * i + 1, k2 = 2 * i + 2, k3 = 2 * i + 3;
        // R0
        RBAR();
        MFMAQ(0, 0, aX, bP);
        LDB4(c1, 0, 1);
        stageA(1, 0, k1);
        // R1
        RBAR();
        MFMAQ(0, 1, aX, c1);
        LDA8(aY, 0, 1);
        stageA(1, 1, k1);
        // R2
        RBAR();
        MFMAQ(1, 1, aY, c1);
        stageB(0, 0, k2);
        WAITV(2);
        // R3
        RBAR();
        MFMAQ(1, 0, aY, bP);
        LDA8(aX, 1, 0);
        LDB4(bQ, 1, 0);
        stageB(0, 1, k2);
        // R4
        RBAR();
        MFMAQ(0, 0, aX, bQ);
        LDB4(c1, 1, 1);
        stageA(0, 0, k2);
        // R5
        RBAR();
        MFMAQ(0, 1, aX, c1);
        LDA8(aY, 1, 1);
        stageA(0, 1, k2);
        // R6
        RBAR();
        MFMAQ(1, 1, aY, c1);
        stageB(1, 0, k3);
        WAITV(2);
        // R7
        RBAR();
        MFMAQ(1, 0, aY, bQ);
        LDA8(aX, 0, 0);
        LDB4(bP, 0, 0);
        stageB(1, 1, k3);
    }

    WAITV(0);
    __syncthreads();

    // ---- epilogue: bias add + per-row (max, sumexp) over this 256-col tile
    float* redM = (float*)(smem + 131072);
    float* redS = (float*)(smem + 135168);
    const int colbase = vt * BN + wc * 64 + lo;
    float bias_n[4];
#pragma unroll
    for (int n = 0; n < 4; ++n) {
        int col = colbase + n * 16;
        bias_n[n] = (col < V) ? bias[col] : 0.0f;
    }
#pragma unroll
    for (int m = 0; m < 8; ++m) {
#pragma unroll
        for (int qq = 0; qq < 4; ++qq) {
            float l[4];
            float vmax = -1e30f;
#pragma unroll
            for (int n = 0; n < 4; ++n) {
                int col = colbase + n * 16;
                float x = (col < V) ? (acc[m][n][qq] + bias_n[n]) : -1e30f;
                l[n] = x;
                vmax = fmaxf(vmax, x);
            }
#pragma unroll
            for (int d = 1; d < 16; d <<= 1) vmax = fmaxf(vmax, __shfl_xor(vmax, d));
            float s = 0.f;
#pragma unroll
            for (int n = 0; n < 4; ++n) s += __expf(l[n] - vmax);
#pragma unroll
            for (int d = 1; d < 16; d <<= 1) s += __shfl_xor(s, d);
            if (lo == 0) {
                int R = wr * 128 + m * 16 + hi * 4 + qq;
                redM[wc * 256 + R] = vmax;
                redS[wc * 256 + R] = s;
            }
        }
    }
    __syncthreads();
    if (t < 256) {
        float M = redM[t], S = redS[t];
#pragma unroll
        for (int w2 = 1; w2 < 4; ++w2) {
            float m2 = redM[w2 * 256 + t], s2 = redS[w2 * 256 + t];
            float nM = fmaxf(M, m2);
            S = S * __expf(M - nM) + s2 * __expf(m2 - nM);
            M = nM;
        }
        size_t row = (size_t)mt * BM + t;
        partials[row * (size_t)NVT + vt] = make_float2(M, S);
    }
}

// ---------------- fp32 true-logit per row (one wave per row) --------------
__global__ __launch_bounds__(256) void true_logit_k(
    const float* __restrict__ emb, const float* __restrict__ wt,
    const float* __restrict__ bias, const int* __restrict__ labels,
    float* __restrict__ tl, int* __restrict__ validf, int NR, int V, int S) {
    int wid = blockIdx.x * 4 + (threadIdx.x >> 6);
    int lane = threadIdx.x & 63;
    if (wid >= NR) return;
    int b = wid / S, s = wid % S;
    int valid = 0;
    float val = 0.f;
    if (s < S - 1) {
        int y = labels[b * S + s + 1];
        if (y != IGNORE_INDEX) {
            valid = 1;
            int ys = (y >= 0 && y < V) ? y : 0;
            const float4* e4 = (const float4*)(emb + ((size_t)b * S + s) * DD);
            const float4* w4 = (const float4*)(wt + (size_t)ys * DD);
            float sum = 0.f;
            for (int i = lane; i < DD / 4; i += 64) {
                float4 aa = e4[i], w = w4[i];
                sum += aa.x * w.x + aa.y * w.y + aa.z * w.z + aa.w * w.w;
            }
#pragma unroll
            for (int d = 1; d < 64; d <<= 1) sum += __shfl_xor(sum, d);
            val = sum + bias[ys];
        }
    }
    if (lane == 0) {
        tl[wid] = val;
        validf[wid] = valid;
    }
}

// ---------------- combine partials -> per-row NLL -> global sum -----------
__global__ __launch_bounds__(256) void reduce_rows_k(
    const float2* __restrict__ partials, const float* __restrict__ tl,
    const int* __restrict__ validf, float* __restrict__ accum, int NR,
    int NVT, int S) {
    int wid = blockIdx.x * 4 + (threadIdx.x >> 6);
    int lane = threadIdx.x & 63;
    if (wid >= NR) return;
    int s = wid % S;
    if (s >= S - 1) return;
    if (!validf[wid]) return;
    float M = -1e30f, Sm = 0.f;
    const float2* p = partials + (size_t)wid * NVT;
    for (int v = lane; v < NVT; v += 64) {
        float2 ms = p[v];
        float nM = fmaxf(M, ms.x);
        Sm = Sm * __expf(M - nM) + ms.y * __expf(ms.x - nM);
        M = nM;
    }
#pragma unroll
    for (int d = 1; d < 64; d <<= 1) {
        float oM = __shfl_xor(M, d), oS = __shfl_xor(Sm, d);
        float nM = fmaxf(M, oM);
        Sm = Sm * __expf(M - nM) + oS * __expf(oM - nM);
        M = nM;
    }
    if (lane == 0) {
        float lse = M + __logf(Sm);
        float nll = lse - tl[wid];
        atomicAdd(&accum[0], nll);
        atomicAdd(&accum[1], 1.0f);
    }
}

__global__ void finalize_k(const float* __restrict__ accum,
                           float* __restrict__ out) {
    out[0] = accum[0] / fmaxf(accum[1], 1.0f);
}

extern "C" void kernel_launch(void* const* d_in, const int* in_sizes, int n_in,
                              void* d_out, int out_size, void* d_ws,
                              size_t ws_size, hipStream_t stream) {
    const float* emb = (const float*)d_in[0];
    const float* wt = (const float*)d_in[1];
    const float* bias = (const float*)d_in[2];
    const int* labels = (const int*)d_in[3];

    const int B = 2, S = 2048;
    const int V = in_sizes[2];            // 50257
    const int NR = B * S;                 // 4096
    const int NVT = (V + BN - 1) / BN;    // 197
    const int Vpad = NVT * BN;            // 50432

    char* p = (char*)d_ws;
    unsigned char* E8 = (unsigned char*)p;
    p += (size_t)NR * DD;
    float2* partials = (float2*)p;
    p += (size_t)NR * NVT * sizeof(float2);
    float* tl = (float*)p;
    p += (size_t)NR * 4;
    int* validf = (int*)p;
    p += (size_t)NR * 4;
    float* accum = (float*)p;
    p += 256;
    unsigned char* W8 = (unsigned char*)p;

    hipMemsetAsync(accum, 0, 8, stream);

    size_t echunks = (size_t)NR * DD / 8;
    convE8_k<<<(int)((echunks + 255) / 256), 256, 0, stream>>>(emb, E8, echunks);

    size_t wchunks = (size_t)Vpad * DD / 8;
    convW8_k<<<8192, 256, 0, stream>>>(wt, W8, V, wchunks);

    hipFuncSetAttribute((const void*)gemm_lse256_k,
                        hipFuncAttributeMaxDynamicSharedMemorySize, LDS_TOTAL);
    gemm_lse256_k<<<NMT * NVT, THREADS, LDS_TOTAL, stream>>>(E8, W8, bias,
                                                             partials, NVT, V);

    true_logit_k<<<NR / 4, 256, 0, stream>>>(emb, wt, bias, labels, tl, validf,
                                             NR, V, S);
    reduce_rows_k<<<NR / 4, 256, 0, stream>>>(partials, tl, validf, accum, NR,
                                              NVT, S);
    finalize_k<<<1, 1, 0, stream>>>(accum, (float*)d_out);
}

// Round 9
// 709.405 us; speedup vs baseline: 5.4695x; 1.1733x over previous
//
#include <hip/hip_runtime.h>

#define IGNORE_INDEX (-100)
#define DD 2048
#define BM 256
#define BN 256
#define BKB 128   // K-tile in BYTES = 128 fp8 elements
#define NKT 16    // DD/128
#define NMT 16    // 4096/BM
#define THREADS 512
#define LDS_TOTAL 139264

typedef __attribute__((ext_vector_type(4))) float f32x4;
typedef __attribute__((ext_vector_type(8))) int i32x8;
typedef __attribute__((ext_vector_type(4))) int i32x4;

// ---- fp32 -> fp8 e4m3 (OCP) pair-pack via HW converter -------------------
__device__ __forceinline__ unsigned cvt8x4(float a, float b, float c, float d) {
    unsigned r = 0;
    r = __builtin_amdgcn_cvt_pk_fp8_f32(a, b, r, false);  // bytes 0-1
    r = __builtin_amdgcn_cvt_pk_fp8_f32(c, d, r, true);   // bytes 2-3
    return r;
}

__device__ __forceinline__ void gload_lds16(const void* g, void* l) {
    __builtin_amdgcn_global_load_lds(
        (const __attribute__((address_space(1))) void*)g,
        (__attribute__((address_space(3))) void*)l, 16, 0, 0);
}

// fp8 layout is PLAIN row-major now: byte c of a row = element c. The
// mfma_scale 16x16x128 fragment wants lane-group hi to hold 32 CONSECUTIVE
// k-bytes (k = hi*32..hi*32+31) => two b128 reads at byte cols hi*32 and
// hi*32+16 (pre-swizzle). No conversion-side permutation needed (r8's
// permutation existed only for the 16x16x32 i64 fragment order).

// ---------------- fp32 -> fp8 conversion (embeddings) ---------------------
__global__ __launch_bounds__(256) void convE8_k(const float* __restrict__ in,
                                                unsigned char* __restrict__ out,
                                                size_t nchunks) {
    size_t i = (size_t)blockIdx.x * 256 + threadIdx.x;
    if (i >= nchunks) return;
    size_t o = i * 8;
    const float* src = in + o;
    float4 a = *(const float4*)src;
    float4 b = *(const float4*)(src + 4);
    uint2 v = { cvt8x4(a.x, a.y, a.z, a.w), cvt8x4(b.x, b.y, b.z, b.w) };
    *(uint2*)(out + o) = v;
}

// ---------------- fp32 -> fp8 conversion (weight, zero-pad to Vpad) -------
__global__ __launch_bounds__(256) void convW8_k(const float* __restrict__ wt,
                                                unsigned char* __restrict__ out,
                                                int V, size_t nchunks) {
    for (size_t i = (size_t)blockIdx.x * 256 + threadIdx.x; i < nchunks;
         i += (size_t)gridDim.x * 256) {
        size_t o = i * 8;
        size_t v = o >> 11;
        uint2 val = {0u, 0u};
        if (v < (size_t)V) {
            const float* src = wt + o;
            float4 a = *(const float4*)src;
            float4 b = *(const float4*)(src + 4);
            val = (uint2){ cvt8x4(a.x, a.y, a.z, a.w), cvt8x4(b.x, b.y, b.z, b.w) };
        }
        *(uint2*)(out + o) = val;
    }
}

// ---------------- 256x256 MX-fp8 pipelined GEMM + online-LSE epilogue -----
// r8's proven one-barrier region schedule, MFMA switched to the MX-scaled
// K=128 instruction (unit scales): mfma_scale_f32_16x16x128_f8f6f4 runs at
// ~2.3x the non-scaled fp8 rate (m21/m148). Byte geometry UNCHANGED:
// same 256-row x 128-B LDS tiles, same XOR swizzle, same stage pattern,
// same vmcnt ledger, same ds_read count (2 x b128 per fragment). Per
// region: 8 MFMA/wave (was 32) covering the same 524 KFLOP quadrant.
//
// LDS map: bufA0 @0, bufB0 @32768, bufA1 @65536, bufB1 @98304 (32K each),
//          redM @131072, redS @135168. Swizzle: byte = R*128 + (cb^((R&7)<<4)).
// Ledger (iter i; buf0=T(2i), buf1=T(2i+1)); 2 gload_lds/wave/region:
//  region | MFMA quadrant (regs from) | reads (for next)     | stage          | waitv
//  R0     | (0,0) aX,bP  [R7']    | c1  <- buf0.B nh1        | buf1.A.h0 2i+1 |
//  R1     | (0,1) aX,c1  [R0]     | aY  <- buf0.A mh1        | buf1.A.h1 2i+1 |
//  R2     | (1,1) aY,c1  [R1,R0]  | --                       | buf0.B.h0 2i+2 | W(2)
//  R3     | (1,0) aY,bP           | aX<-buf1.A mh0, bQ<-buf1.B nh0 | buf0.B.h1 2i+2 |
//  R4     | (0,0) aX,bQ  [R3]     | c1  <- buf1.B nh1        | buf0.A.h0 2i+2 |
//  R5     | (0,1) aX,c1  [R4]     | aY  <- buf1.A mh1        | buf0.A.h1 2i+2 |
//  R6     | (1,1) aY,c1  [R5,R4]  | --                       | buf1.B.h0 2i+3 | W(2)
//  R7     | (1,0) aY,bQ           | aX<-buf0.A mh0, bP<-buf0.B nh0 | buf1.B.h1 2i+3 |

#define LDAF(DST, B, MH)                                                    \
    do {                                                                    \
        _Pragma("unroll") for (int mm = 0; mm < 4; ++mm) {                  \
            i32x4 u = *(const i32x4*)(smem + offA[B][0] + (MH)*8192 +       \
                                      mm * 2048);                           \
            i32x4 w = *(const i32x4*)(smem + offA[B][1] + (MH)*8192 +       \
                                      mm * 2048);                           \
            DST[mm] = __builtin_shufflevector(u, w, 0, 1, 2, 3, 4, 5, 6, 7);\
        }                                                                   \
    } while (0)
#define LDBF(DST, B, NH)                                                    \
    do {                                                                    \
        _Pragma("unroll") for (int nn = 0; nn < 2; ++nn) {                  \
            i32x4 u = *(const i32x4*)(smem + offB[B][0] + (NH)*4096 +       \
                                      nn * 2048);                           \
            i32x4 w = *(const i32x4*)(smem + offB[B][1] + (NH)*4096 +       \
                                      nn * 2048);                           \
            DST[nn] = __builtin_shufflevector(u, w, 0, 1, 2, 3, 4, 5, 6, 7);\
        }                                                                   \
    } while (0)
// unit scales: e8m0 exponent 127 -> 2^0 = 1.0 (byte 0 selected by opsel=0)
#define MFMAQ(MH, NH, AARR, BARR)                                           \
    do {                                                                    \
        __builtin_amdgcn_s_setprio(1);                                      \
        _Pragma("unroll") for (int mm = 0; mm < 4; ++mm)                    \
        _Pragma("unroll") for (int nn = 0; nn < 2; ++nn)                    \
            acc[(MH)*4 + mm][(NH)*2 + nn] =                                 \
                __builtin_amdgcn_mfma_scale_f32_16x16x128_f8f6f4(           \
                    AARR[mm], BARR[nn], acc[(MH)*4 + mm][(NH)*2 + nn],      \
                    0, 0, 0, 0x7F7F7F7F, 0, 0x7F7F7F7F);                    \
        __builtin_amdgcn_s_setprio(0);                                      \
    } while (0)
#define RBAR()                                                              \
    do {                                                                    \
        __builtin_amdgcn_s_barrier();                                       \
        __builtin_amdgcn_sched_barrier(0);                                  \
    } while (0)
#define WAITV(N) asm volatile("s_waitcnt vmcnt(" #N ")" ::: "memory")

__global__ __launch_bounds__(THREADS, 2) void gemm_lse256_k(
    const unsigned char* __restrict__ E8,    // [4096][2048 B] fp8
    const unsigned char* __restrict__ W8,    // [Vpad][2048 B] fp8
    const float* __restrict__ bias,          // [V]
    float2* __restrict__ partials,           // [NR][NVT]
    int NVT, int V) {
    extern __shared__ char smem[];
    const int t = threadIdx.x;
    const int lane = t & 63;
    const int wave = t >> 6;
    const int wr = wave >> 2;   // 0..1
    const int wc = wave & 3;    // 0..3
    const int lo = lane & 15;
    const int hi = lane >> 4;

    // bijective XCD swizzle (m204)
    const int nwg = NMT * NVT;
    const int xcd = blockIdx.x & 7;
    const int idx = blockIdx.x >> 3;
    const int q8 = nwg >> 3, r8 = nwg & 7;
    const int swz = (xcd < r8 ? xcd * (q8 + 1) : r8 * (q8 + 1) + (xcd - r8) * q8) + idx;
    const int mt = swz & (NMT - 1);
    const int vt = swz >> 4;

    const unsigned char* Ag = E8 + (size_t)mt * BM * DD;
    const unsigned char* Bg = W8 + (size_t)vt * BN * DD;

    f32x4 acc[8][4];
#pragma unroll
    for (int m = 0; m < 8; ++m)
#pragma unroll
        for (int n = 0; n < 4; ++n) acc[m][n] = (f32x4){0.f, 0.f, 0.f, 0.f};
    i32x8 aX[4], aY[4], bP[2], bQ[2], c1[2];

    // ---- precomputed LDS read base offsets (loop-invariant) ----
    const int xorm = (lo & 7) << 4;
    int cbx[2];
    cbx[0] = (hi * 32) ^ xorm;
    cbx[1] = (hi * 32 + 16) ^ xorm;
    int offA[2][2], offB[2][2];  // [buf][half] byte offsets into smem
#pragma unroll
    for (int b = 0; b < 2; ++b)
#pragma unroll
        for (int k = 0; k < 2; ++k) {
            offA[b][k] = b * 65536 + (wr * 128 + lo) * 128 + cbx[k];
            offB[b][k] = 32768 + b * 65536 + (wc * 64 + lo) * 128 + cbx[k];
        }

    // ---- precomputed stage pointers (loop-invariant) ----
    const int srow = lane >> 3;
    const int cbs = ((lane & 7) * 16) ^ (srow << 4);
    const unsigned char* gA[2][2];  // [j][h]
    const unsigned char* gB[2][2];
#pragma unroll
    for (int j = 0; j < 2; ++j)
#pragma unroll
        for (int h = 0; h < 2; ++h) {
            int row = (wave * 2 + j) * 8 + srow;
            gA[j][h] = Ag + (size_t)(h * 128 + row) * DD + cbs;
            gB[j][h] = Bg + (size_t)(h * 128 + row) * DD + cbs;
        }
    const int wbyte = wave * 2048;

    auto stageA = [&](int b, int h, int kt) {
        int ktc = (kt & (NKT - 1)) * BKB;
#pragma unroll
        for (int j = 0; j < 2; ++j)
            gload_lds16(gA[j][h] + ktc,
                        smem + b * 65536 + h * 16384 + wbyte + j * 1024);
    };
    auto stageB = [&](int b, int h, int kt) {
        int ktc = (kt & (NKT - 1)) * BKB;
#pragma unroll
        for (int j = 0; j < 2; ++j)
            gload_lds16(gB[j][h] + ktc,
                        smem + 32768 + b * 65536 + h * 16384 + wbyte + j * 1024);
    };

    // prologue: T0 -> buf0 (4 halves), T1.B -> buf1 (2 halves)
    stageA(0, 0, 0); stageA(0, 1, 0);
    stageB(0, 0, 0); stageB(0, 1, 0);
    stageB(1, 0, 1); stageB(1, 1, 1);
    WAITV(4);   // T0 landed; T1.B (4 loads) in flight
    __builtin_amdgcn_s_barrier();
    __builtin_amdgcn_sched_barrier(0);
    // pre-load R0's operands from buf0
    LDAF(aX, 0, 0);
    LDBF(bP, 0, 0);

    for (int i = 0; i < NKT / 2; ++i) {
        const int k1 = 2 * i + 1, k2 = 2 * i + 2, k3 = 2 * i + 3;
        // R0
        RBAR();
        MFMAQ(0, 0, aX, bP);
        LDBF(c1, 0, 1);
        stageA(1, 0, k1);
        // R1
        RBAR();
        MFMAQ(0, 1, aX, c1);
        LDAF(aY, 0, 1);
        stageA(1, 1, k1);
        // R2
        RBAR();
        MFMAQ(1, 1, aY, c1);
        stageB(0, 0, k2);
        WAITV(2);
        // R3
        RBAR();
        MFMAQ(1, 0, aY, bP);
        LDAF(aX, 1, 0);
        LDBF(bQ, 1, 0);
        stageB(0, 1, k2);
        // R4
        RBAR();
        MFMAQ(0, 0, aX, bQ);
        LDBF(c1, 1, 1);
        stageA(0, 0, k2);
        // R5
        RBAR();
        MFMAQ(0, 1, aX, c1);
        LDAF(aY, 1, 1);
        stageA(0, 1, k2);
        // R6
        RBAR();
        MFMAQ(1, 1, aY, c1);
        stageB(1, 0, k3);
        WAITV(2);
        // R7
        RBAR();
        MFMAQ(1, 0, aY, bQ);
        LDAF(aX, 0, 0);
        LDBF(bP, 0, 0);
        stageB(1, 1, k3);
    }

    WAITV(0);
    __syncthreads();

    // ---- epilogue: bias add + per-row (max, sumexp) over this 256-col tile
    float* redM = (float*)(smem + 131072);
    float* redS = (float*)(smem + 135168);
    const int colbase = vt * BN + wc * 64 + lo;
    float bias_n[4];
#pragma unroll
    for (int n = 0; n < 4; ++n) {
        int col = colbase + n * 16;
        bias_n[n] = (col < V) ? bias[col] : 0.0f;
    }
#pragma unroll
    for (int m = 0; m < 8; ++m) {
#pragma unroll
        for (int qq = 0; qq < 4; ++qq) {
            float l[4];
            float vmax = -1e30f;
#pragma unroll
            for (int n = 0; n < 4; ++n) {
                int col = colbase + n * 16;
                float x = (col < V) ? (acc[m][n][qq] + bias_n[n]) : -1e30f;
                l[n] = x;
                vmax = fmaxf(vmax, x);
            }
#pragma unroll
            for (int d = 1; d < 16; d <<= 1) vmax = fmaxf(vmax, __shfl_xor(vmax, d));
            float s = 0.f;
#pragma unroll
            for (int n = 0; n < 4; ++n) s += __expf(l[n] - vmax);
#pragma unroll
            for (int d = 1; d < 16; d <<= 1) s += __shfl_xor(s, d);
            if (lo == 0) {
                int R = wr * 128 + m * 16 + hi * 4 + qq;
                redM[wc * 256 + R] = vmax;
                redS[wc * 256 + R] = s;
            }
        }
    }
    __syncthreads();
    if (t < 256) {
        float M = redM[t], S = redS[t];
#pragma unroll
        for (int w2 = 1; w2 < 4; ++w2) {
            float m2 = redM[w2 * 256 + t], s2 = redS[w2 * 256 + t];
            float nM = fmaxf(M, m2);
            S = S * __expf(M - nM) + s2 * __expf(m2 - nM);
            M = nM;
        }
        size_t row = (size_t)mt * BM + t;
        partials[row * (size_t)NVT + vt] = make_float2(M, S);
    }
}

// ---------------- fp32 true-logit per row (one wave per row) --------------
__global__ __launch_bounds__(256) void true_logit_k(
    const float* __restrict__ emb, const float* __restrict__ wt,
    const float* __restrict__ bias, const int* __restrict__ labels,
    float* __restrict__ tl, int* __restrict__ validf, int NR, int V, int S) {
    int wid = blockIdx.x * 4 + (threadIdx.x >> 6);
    int lane = threadIdx.x & 63;
    if (wid >= NR) return;
    int b = wid / S, s = wid % S;
    int valid = 0;
    float val = 0.f;
    if (s < S - 1) {
        int y = labels[b * S + s + 1];
        if (y != IGNORE_INDEX) {
            valid = 1;
            int ys = (y >= 0 && y < V) ? y : 0;
            const float4* e4 = (const float4*)(emb + ((size_t)b * S + s) * DD);
            const float4* w4 = (const float4*)(wt + (size_t)ys * DD);
            float sum = 0.f;
            for (int i = lane; i < DD / 4; i += 64) {
                float4 aa = e4[i], w = w4[i];
                sum += aa.x * w.x + aa.y * w.y + aa.z * w.z + aa.w * w.w;
            }
#pragma unroll
            for (int d = 1; d < 64; d <<= 1) sum += __shfl_xor(sum, d);
            val = sum + bias[ys];
        }
    }
    if (lane == 0) {
        tl[wid] = val;
        validf[wid] = valid;
    }
}

// ---------------- combine partials -> per-row NLL -> global sum -----------
__global__ __launch_bounds__(256) void reduce_rows_k(
    const float2* __restrict__ partials, const float* __restrict__ tl,
    const int* __restrict__ validf, float* __restrict__ accum, int NR,
    int NVT, int S) {
    int wid = blockIdx.x * 4 + (threadIdx.x >> 6);
    int lane = threadIdx.x & 63;
    if (wid >= NR) return;
    int s = wid % S;
    if (s >= S - 1) return;
    if (!validf[wid]) return;
    float M = -1e30f, Sm = 0.f;
    const float2* p = partials + (size_t)wid * NVT;
    for (int v = lane; v < NVT; v += 64) {
        float2 ms = p[v];
        float nM = fmaxf(M, ms.x);
        Sm = Sm * __expf(M - nM) + ms.y * __expf(ms.x - nM);
        M = nM;
    }
#pragma unroll
    for (int d = 1; d < 64; d <<= 1) {
        float oM = __shfl_xor(M, d), oS = __shfl_xor(Sm, d);
        float nM = fmaxf(M, oM);
        Sm = Sm * __expf(M - nM) + oS * __expf(oM - nM);
        M = nM;
    }
    if (lane == 0) {
        float lse = M + __logf(Sm);
        float nll = lse - tl[wid];
        atomicAdd(&accum[0], nll);
        atomicAdd(&accum[1], 1.0f);
    }
}

__global__ void finalize_k(const float* __restrict__ accum,
                           float* __restrict__ out) {
    out[0] = accum[0] / fmaxf(accum[1], 1.0f);
}

extern "C" void kernel_launch(void* const* d_in, const int* in_sizes, int n_in,
                              void* d_out, int out_size, void* d_ws,
                              size_t ws_size, hipStream_t stream) {
    const float* emb = (const float*)d_in[0];
    const float* wt = (const float*)d_in[1];
    const float* bias = (const float*)d_in[2];
    const int* labels = (const int*)d_in[3];

    const int B = 2, S = 2048;
    const int V = in_sizes[2];            // 50257
    const int NR = B * S;                 // 4096
    const int NVT = (V + BN - 1) / BN;    // 197
    const int Vpad = NVT * BN;            // 50432

    char* p = (char*)d_ws;
    unsigned char* E8 = (unsigned char*)p;
    p += (size_t)NR * DD;
    float2* partials = (float2*)p;
    p += (size_t)NR * NVT * sizeof(float2);
    float* tl = (float*)p;
    p += (size_t)NR * 4;
    int* validf = (int*)p;
    p += (size_t)NR * 4;
    float* accum = (float*)p;
    p += 256;
    unsigned char* W8 = (unsigned char*)p;

    hipMemsetAsync(accum, 0, 8, stream);

    size_t echunks = (size_t)NR * DD / 8;
    convE8_k<<<(int)((echunks + 255) / 256), 256, 0, stream>>>(emb, E8, echunks);

    size_t wchunks = (size_t)Vpad * DD / 8;
    convW8_k<<<8192, 256, 0, stream>>>(wt, W8, V, wchunks);

    hipFuncSetAttribute((const void*)gemm_lse256_k,
                        hipFuncAttributeMaxDynamicSharedMemorySize, LDS_TOTAL);
    gemm_lse256_k<<<NMT * NVT, THREADS, LDS_TOTAL, stream>>>(E8, W8, bias,
                                                             partials, NVT, V);

    true_logit_k<<<NR / 4, 256, 0, stream>>>(emb, wt, bias, labels, tl, validf,
                                             NR, V, S);
    reduce_rows_k<<<NR / 4, 256, 0, stream>>>(partials, tl, validf, accum, NR,
                                              NVT, S);
    finalize_k<<<1, 1, 0, stream>>>(accum, (float*)d_out);
}

// Round 10
// 689.775 us; speedup vs baseline: 5.6252x; 1.0285x over previous
//
#include <hip/hip_runtime.h>

#define IGNORE_INDEX (-100)
#define DD 2048
#define BM 256
#define BN 256
#define BKB 128   // K-tile in BYTES = 128 fp8 elements
#define NKT 16    // DD/128
#define NMT 16    // 4096/BM
#define THREADS 512
#define LDS_TOTAL 139264

typedef __attribute__((ext_vector_type(4))) float f32x4;
typedef __attribute__((ext_vector_type(8))) int i32x8;
typedef __attribute__((ext_vector_type(4))) int i32x4;

// ---- fp32 -> fp8 e4m3 (OCP) pair-pack via HW converter -------------------
__device__ __forceinline__ unsigned cvt8x4(float a, float b, float c, float d) {
    unsigned r = 0;
    r = __builtin_amdgcn_cvt_pk_fp8_f32(a, b, r, false);  // bytes 0-1
    r = __builtin_amdgcn_cvt_pk_fp8_f32(c, d, r, true);   // bytes 2-3
    return r;
}

__device__ __forceinline__ void gload_lds16(const void* g, void* l) {
    __builtin_amdgcn_global_load_lds(
        (const __attribute__((address_space(1))) void*)g,
        (__attribute__((address_space(3))) void*)l, 16, 0, 0);
}

// Permuted fp8 layout: within each 128-B k-tile, byte c holds element
//   k(c) = ((c>>4)&3)*32 + ((c>>6)&1)*16 + (c&15)        [bijective]
// chosen so the CONFLICT-FREE r8 read columns (hi*16 and 64+hi*16, XOR'd
// with the row swizzle) deliver lane-k hi*32+0..15 and hi*32+16..31 — the
// v8i32 fragment of mfma_scale_16x16x128 (order validated in r9, absmax=0).
// r9's "consecutive bytes" columns (hi*32, hi*32+16) measured 4.0e7 bank
// conflicts; r8's columns measured 0 — so keep r8 addresses, permute data.
// For 8-aligned c: k(c)..k(c)+7 are 8 consecutive input elements starting at
//   kb(c) = ((c>>4)&3)*32 + ((c>>6)&1)*16 + (c&8).

// ---------------- fp32 -> fp8 conversion (embeddings, permuted) -----------
__global__ __launch_bounds__(256) void convE8_k(const float* __restrict__ in,
                                                unsigned char* __restrict__ out,
                                                size_t nchunks) {
    size_t i = (size_t)blockIdx.x * 256 + threadIdx.x;
    if (i >= nchunks) return;
    size_t o = i * 8;
    unsigned c = (unsigned)o & 127;
    unsigned kb = ((c >> 4) & 3) * 32 + ((c >> 6) & 1) * 16 + (c & 8);
    const float* src = in + (o & ~(size_t)127) + kb;
    float4 a = *(const float4*)src;
    float4 b = *(const float4*)(src + 4);
    uint2 v = { cvt8x4(a.x, a.y, a.z, a.w), cvt8x4(b.x, b.y, b.z, b.w) };
    *(uint2*)(out + o) = v;
}

// ---------------- fp32 -> fp8 conversion (weight, permuted, zero-pad) -----
__global__ __launch_bounds__(256) void convW8_k(const float* __restrict__ wt,
                                                unsigned char* __restrict__ out,
                                                int V, size_t nchunks) {
    for (size_t i = (size_t)blockIdx.x * 256 + threadIdx.x; i < nchunks;
         i += (size_t)gridDim.x * 256) {
        size_t o = i * 8;
        size_t v = o >> 11;
        uint2 val = {0u, 0u};
        if (v < (size_t)V) {
            unsigned c = (unsigned)o & 127;
            unsigned kb = ((c >> 4) & 3) * 32 + ((c >> 6) & 1) * 16 + (c & 8);
            const float* src = wt + (o & ~(size_t)127) + kb;
            float4 a = *(const float4*)src;
            float4 b = *(const float4*)(src + 4);
            val = (uint2){ cvt8x4(a.x, a.y, a.z, a.w), cvt8x4(b.x, b.y, b.z, b.w) };
        }
        *(uint2*)(out + o) = val;
    }
}

// ---------------- 256x256 MX-fp8 pipelined GEMM + online-LSE epilogue -----
// r9's structure with r8's conflict-free LDS read addresses (data permuted
// globally instead). One barrier per region; 8 mfma_scale_16x16x128 per
// wave per region; same stage pattern / vmcnt ledger / swizzle as r4-r9.
//
// LDS map: bufA0 @0, bufB0 @32768, bufA1 @65536, bufB1 @98304 (32K each),
//          redM @131072, redS @135168. Swizzle: byte = R*128 + (cb^((R&7)<<4)).
// Ledger (iter i; buf0=T(2i), buf1=T(2i+1)); 2 gload_lds/wave/region:
//  region | MFMA quadrant (regs from) | reads (for next)     | stage          | waitv
//  R0     | (0,0) aX,bP  [R7']    | c1  <- buf0.B nh1        | buf1.A.h0 2i+1 |
//  R1     | (0,1) aX,c1  [R0]     | aY  <- buf0.A mh1        | buf1.A.h1 2i+1 |
//  R2     | (1,1) aY,c1  [R1,R0]  | --                       | buf0.B.h0 2i+2 | W(2)
//  R3     | (1,0) aY,bP           | aX<-buf1.A mh0, bQ<-buf1.B nh0 | buf0.B.h1 2i+2 |
//  R4     | (0,0) aX,bQ  [R3]     | c1  <- buf1.B nh1        | buf0.A.h0 2i+2 |
//  R5     | (0,1) aX,c1  [R4]     | aY  <- buf1.A mh1        | buf0.A.h1 2i+2 |
//  R6     | (1,1) aY,c1  [R5,R4]  | --                       | buf1.B.h0 2i+3 | W(2)
//  R7     | (1,0) aY,bQ           | aX<-buf0.A mh0, bP<-buf0.B nh0 | buf1.B.h1 2i+3 |

#define LDAF(DST, B, MH)                                                    \
    do {                                                                    \
        _Pragma("unroll") for (int mm = 0; mm < 4; ++mm) {                  \
            i32x4 u = *(const i32x4*)(smem + offA[B][0] + (MH)*8192 +       \
                                      mm * 2048);                           \
            i32x4 w = *(const i32x4*)(smem + offA[B][1] + (MH)*8192 +       \
                                      mm * 2048);                           \
            DST[mm] = __builtin_shufflevector(u, w, 0, 1, 2, 3, 4, 5, 6, 7);\
        }                                                                   \
    } while (0)
#define LDBF(DST, B, NH)                                                    \
    do {                                                                    \
        _Pragma("unroll") for (int nn = 0; nn < 2; ++nn) {                  \
            i32x4 u = *(const i32x4*)(smem + offB[B][0] + (NH)*4096 +       \
                                      nn * 2048);                           \
            i32x4 w = *(const i32x4*)(smem + offB[B][1] + (NH)*4096 +       \
                                      nn * 2048);                           \
            DST[nn] = __builtin_shufflevector(u, w, 0, 1, 2, 3, 4, 5, 6, 7);\
        }                                                                   \
    } while (0)
// unit scales: e8m0 exponent 127 -> 2^0 = 1.0
#define MFMAQ(MH, NH, AARR, BARR)                                           \
    do {                                                                    \
        __builtin_amdgcn_s_setprio(1);                                      \
        _Pragma("unroll") for (int mm = 0; mm < 4; ++mm)                    \
        _Pragma("unroll") for (int nn = 0; nn < 2; ++nn)                    \
            acc[(MH)*4 + mm][(NH)*2 + nn] =                                 \
                __builtin_amdgcn_mfma_scale_f32_16x16x128_f8f6f4(           \
                    AARR[mm], BARR[nn], acc[(MH)*4 + mm][(NH)*2 + nn],      \
                    0, 0, 0, 0x7F7F7F7F, 0, 0x7F7F7F7F);                    \
        __builtin_amdgcn_s_setprio(0);                                      \
    } while (0)
#define RBAR()                                                              \
    do {                                                                    \
        __builtin_amdgcn_s_barrier();                                       \
        __builtin_amdgcn_sched_barrier(0);                                  \
    } while (0)
#define WAITV(N) asm volatile("s_waitcnt vmcnt(" #N ")" ::: "memory")

__global__ __launch_bounds__(THREADS, 2) void gemm_lse256_k(
    const unsigned char* __restrict__ E8,    // [4096][2048 B] permuted fp8
    const unsigned char* __restrict__ W8,    // [Vpad][2048 B] permuted fp8
    const float* __restrict__ bias,          // [V]
    float2* __restrict__ partials,           // [NR][NVT]
    int NVT, int V) {
    extern __shared__ char smem[];
    const int t = threadIdx.x;
    const int lane = t & 63;
    const int wave = t >> 6;
    const int wr = wave >> 2;   // 0..1
    const int wc = wave & 3;    // 0..3
    const int lo = lane & 15;
    const int hi = lane >> 4;

    // bijective XCD swizzle (m204)
    const int nwg = NMT * NVT;
    const int xcd = blockIdx.x & 7;
    const int idx = blockIdx.x >> 3;
    const int q8 = nwg >> 3, r8 = nwg & 7;
    const int swz = (xcd < r8 ? xcd * (q8 + 1) : r8 * (q8 + 1) + (xcd - r8) * q8) + idx;
    const int mt = swz & (NMT - 1);
    const int vt = swz >> 4;

    const unsigned char* Ag = E8 + (size_t)mt * BM * DD;
    const unsigned char* Bg = W8 + (size_t)vt * BN * DD;

    f32x4 acc[8][4];
#pragma unroll
    for (int m = 0; m < 8; ++m)
#pragma unroll
        for (int n = 0; n < 4; ++n) acc[m][n] = (f32x4){0.f, 0.f, 0.f, 0.f};
    i32x8 aX[4], aY[4], bP[2], bQ[2], c1[2];

    // ---- precomputed LDS read base offsets (r8's conflict-free columns) ----
    const int xorm = (lo & 7) << 4;
    int cbx[2];
    cbx[0] = (hi * 16) ^ xorm;
    cbx[1] = (64 + hi * 16) ^ xorm;
    int offA[2][2], offB[2][2];  // [buf][half] byte offsets into smem
#pragma unroll
    for (int b = 0; b < 2; ++b)
#pragma unroll
        for (int k = 0; k < 2; ++k) {
            offA[b][k] = b * 65536 + (wr * 128 + lo) * 128 + cbx[k];
            offB[b][k] = 32768 + b * 65536 + (wc * 64 + lo) * 128 + cbx[k];
        }

    // ---- precomputed stage pointers (loop-invariant) ----
    const int srow = lane >> 3;
    const int cbs = ((lane & 7) * 16) ^ (srow << 4);
    const unsigned char* gA[2][2];  // [j][h]
    const unsigned char* gB[2][2];
#pragma unroll
    for (int j = 0; j < 2; ++j)
#pragma unroll
        for (int h = 0; h < 2; ++h) {
            int row = (wave * 2 + j) * 8 + srow;
            gA[j][h] = Ag + (size_t)(h * 128 + row) * DD + cbs;
            gB[j][h] = Bg + (size_t)(h * 128 + row) * DD + cbs;
        }
    const int wbyte = wave * 2048;

    auto stageA = [&](int b, int h, int kt) {
        int ktc = (kt & (NKT - 1)) * BKB;
#pragma unroll
        for (int j = 0; j < 2; ++j)
            gload_lds16(gA[j][h] + ktc,
                        smem + b * 65536 + h * 16384 + wbyte + j * 1024);
    };
    auto stageB = [&](int b, int h, int kt) {
        int ktc = (kt & (NKT - 1)) * BKB;
#pragma unroll
        for (int j = 0; j < 2; ++j)
            gload_lds16(gB[j][h] + ktc,
                        smem + 32768 + b * 65536 + h * 16384 + wbyte + j * 1024);
    };

    // prologue: T0 -> buf0 (4 halves), T1.B -> buf1 (2 halves)
    stageA(0, 0, 0); stageA(0, 1, 0);
    stageB(0, 0, 0); stageB(0, 1, 0);
    stageB(1, 0, 1); stageB(1, 1, 1);
    WAITV(4);   // T0 landed; T1.B (4 loads) in flight
    __builtin_amdgcn_s_barrier();
    __builtin_amdgcn_sched_barrier(0);
    // pre-load R0's operands from buf0
    LDAF(aX, 0, 0);
    LDBF(bP, 0, 0);

    for (int i = 0; i < NKT / 2; ++i) {
        const int k1 = 2 * i + 1, k2 = 2 * i + 2, k3 = 2 * i + 3;
        // R0
        RBAR();
        MFMAQ(0, 0, aX, bP);
        LDBF(c1, 0, 1);
        stageA(1, 0, k1);
        // R1
        RBAR();
        MFMAQ(0, 1, aX, c1);
        LDAF(aY, 0, 1);
        stageA(1, 1, k1);
        // R2
        RBAR();
        MFMAQ(1, 1, aY, c1);
        stageB(0, 0, k2);
        WAITV(2);
        // R3
        RBAR();
        MFMAQ(1, 0, aY, bP);
        LDAF(aX, 1, 0);
        LDBF(bQ, 1, 0);
        stageB(0, 1, k2);
        // R4
        RBAR();
        MFMAQ(0, 0, aX, bQ);
        LDBF(c1, 1, 1);
        stageA(0, 0, k2);
        // R5
        RBAR();
        MFMAQ(0, 1, aX, c1);
        LDAF(aY, 1, 1);
        stageA(0, 1, k2);
        // R6
        RBAR();
        MFMAQ(1, 1, aY, c1);
        stageB(1, 0, k3);
        WAITV(2);
        // R7
        RBAR();
        MFMAQ(1, 0, aY, bQ);
        LDAF(aX, 0, 0);
        LDBF(bP, 0, 0);
        stageB(1, 1, k3);
    }

    WAITV(0);
    __syncthreads();

    // ---- epilogue: bias add + per-row (max, sumexp) over this 256-col tile
    float* redM = (float*)(smem + 131072);
    float* redS = (float*)(smem + 135168);
    const int colbase = vt * BN + wc * 64 + lo;
    float bias_n[4];
#pragma unroll
    for (int n = 0; n < 4; ++n) {
        int col = colbase + n * 16;
        bias_n[n] = (col < V) ? bias[col] : 0.0f;
    }
#pragma unroll
    for (int m = 0; m < 8; ++m) {
#pragma unroll
        for (int qq = 0; qq < 4; ++qq) {
            float l[4];
            float vmax = -1e30f;
#pragma unroll
            for (int n = 0; n < 4; ++n) {
                int col = colbase + n * 16;
                float x = (col < V) ? (acc[m][n][qq] + bias_n[n]) : -1e30f;
                l[n] = x;
                vmax = fmaxf(vmax, x);
            }
#pragma unroll
            for (int d = 1; d < 16; d <<= 1) vmax = fmaxf(vmax, __shfl_xor(vmax, d));
            float s = 0.f;
#pragma unroll
            for (int n = 0; n < 4; ++n) s += __expf(l[n] - vmax);
#pragma unroll
            for (int d = 1; d < 16; d <<= 1) s += __shfl_xor(s, d);
            if (lo == 0) {
                int R = wr * 128 + m * 16 + hi * 4 + qq;
                redM[wc * 256 + R] = vmax;
                redS[wc * 256 + R] = s;
            }
        }
    }
    __syncthreads();
    if (t < 256) {
        float M = redM[t], S = redS[t];
#pragma unroll
        for (int w2 = 1; w2 < 4; ++w2) {
            float m2 = redM[w2 * 256 + t], s2 = redS[w2 * 256 + t];
            float nM = fmaxf(M, m2);
            S = S * __expf(M - nM) + s2 * __expf(m2 - nM);
            M = nM;
        }
        size_t row = (size_t)mt * BM + t;
        partials[row * (size_t)NVT + vt] = make_float2(M, S);
    }
}

// ---------------- fp32 true-logit per row (one wave per row) --------------
__global__ __launch_bounds__(256) void true_logit_k(
    const float* __restrict__ emb, const float* __restrict__ wt,
    const float* __restrict__ bias, const int* __restrict__ labels,
    float* __restrict__ tl, int* __restrict__ validf, int NR, int V, int S) {
    int wid = blockIdx.x * 4 + (threadIdx.x >> 6);
    int lane = threadIdx.x & 63;
    if (wid >= NR) return;
    int b = wid / S, s = wid % S;
    int valid = 0;
    float val = 0.f;
    if (s < S - 1) {
        int y = labels[b * S + s + 1];
        if (y != IGNORE_INDEX) {
            valid = 1;
            int ys = (y >= 0 && y < V) ? y : 0;
            const float4* e4 = (const float4*)(emb + ((size_t)b * S + s) * DD);
            const float4* w4 = (const float4*)(wt + (size_t)ys * DD);
            float sum = 0.f;
            for (int i = lane; i < DD / 4; i += 64) {
                float4 aa = e4[i], w = w4[i];
                sum += aa.x * w.x + aa.y * w.y + aa.z * w.z + aa.w * w.w;
            }
#pragma unroll
            for (int d = 1; d < 64; d <<= 1) sum += __shfl_xor(sum, d);
            val = sum + bias[ys];
        }
    }
    if (lane == 0) {
        tl[wid] = val;
        validf[wid] = valid;
    }
}

// ---------------- combine partials -> per-row NLL -> global sum -----------
__global__ __launch_bounds__(256) void reduce_rows_k(
    const float2* __restrict__ partials, const float* __restrict__ tl,
    const int* __restrict__ validf, float* __restrict__ accum, int NR,
    int NVT, int S) {
    int wid = blockIdx.x * 4 + (threadIdx.x >> 6);
    int lane = threadIdx.x & 63;
    if (wid >= NR) return;
    int s = wid % S;
    if (s >= S - 1) return;
    if (!validf[wid]) return;
    float M = -1e30f, Sm = 0.f;
    const float2* p = partials + (size_t)wid * NVT;
    for (int v = lane; v < NVT; v += 64) {
        float2 ms = p[v];
        float nM = fmaxf(M, ms.x);
        Sm = Sm * __expf(M - nM) + ms.y * __expf(ms.x - nM);
        M = nM;
    }
#pragma unroll
    for (int d = 1; d < 64; d <<= 1) {
        float oM = __shfl_xor(M, d), oS = __shfl_xor(Sm, d);
        float nM = fmaxf(M, oM);
        Sm = Sm * __expf(M - nM) + oS * __expf(oM - nM);
        M = nM;
    }
    if (lane == 0) {
        float lse = M + __logf(Sm);
        float nll = lse - tl[wid];
        atomicAdd(&accum[0], nll);
        atomicAdd(&accum[1], 1.0f);
    }
}

__global__ void finalize_k(const float* __restrict__ accum,
                           float* __restrict__ out) {
    out[0] = accum[0] / fmaxf(accum[1], 1.0f);
}

extern "C" void kernel_launch(void* const* d_in, const int* in_sizes, int n_in,
                              void* d_out, int out_size, void* d_ws,
                              size_t ws_size, hipStream_t stream) {
    const float* emb = (const float*)d_in[0];
    const float* wt = (const float*)d_in[1];
    const float* bias = (const float*)d_in[2];
    const int* labels = (const int*)d_in[3];

    const int B = 2, S = 2048;
    const int V = in_sizes[2];            // 50257
    const int NR = B * S;                 // 4096
    const int NVT = (V + BN - 1) / BN;    // 197
    const int Vpad = NVT * BN;            // 50432

    char* p = (char*)d_ws;
    unsigned char* E8 = (unsigned char*)p;
    p += (size_t)NR * DD;
    float2* partials = (float2*)p;
    p += (size_t)NR * NVT * sizeof(float2);
    float* tl = (float*)p;
    p += (size_t)NR * 4;
    int* validf = (int*)p;
    p += (size_t)NR * 4;
    float* accum = (float*)p;
    p += 256;
    unsigned char* W8 = (unsigned char*)p;

    hipMemsetAsync(accum, 0, 8, stream);

    size_t echunks = (size_t)NR * DD / 8;
    convE8_k<<<(int)((echunks + 255) / 256), 256, 0, stream>>>(emb, E8, echunks);

    size_t wchunks = (size_t)Vpad * DD / 8;
    convW8_k<<<8192, 256, 0, stream>>>(wt, W8, V, wchunks);

    hipFuncSetAttribute((const void*)gemm_lse256_k,
                        hipFuncAttributeMaxDynamicSharedMemorySize, LDS_TOTAL);
    gemm_lse256_k<<<NMT * NVT, THREADS, LDS_TOTAL, stream>>>(E8, W8, bias,
                                                             partials, NVT, V);

    true_logit_k<<<NR / 4, 256, 0, stream>>>(emb, wt, bias, labels, tl, validf,
                                             NR, V, S);
    reduce_rows_k<<<NR / 4, 256, 0, stream>>>(partials, tl, validf, accum, NR,
                                              NVT, S);
    finalize_k<<<1, 1, 0, stream>>>(accum, (float*)d_out);
}

// Round 11
// 685.519 us; speedup vs baseline: 5.6601x; 1.0062x over previous
//
#include <hip/hip_runtime.h>

#define IGNORE_INDEX (-100)
#define DD 2048
#define BM 256
#define BN 256
#define BKB 128   // K-tile in BYTES = 128 fp8 elements
#define NKT 16    // DD/128
#define NMT 16    // 4096/BM
#define THREADS 512
#define LDS_TOTAL 139264

typedef __attribute__((ext_vector_type(4))) float f32x4;
typedef __attribute__((ext_vector_type(8))) int i32x8;
typedef __attribute__((ext_vector_type(4))) int i32x4;

// ---- fp32 -> fp8 e4m3 (OCP) pair-pack via HW converter -------------------
__device__ __forceinline__ unsigned cvt8x4(float a, float b, float c, float d) {
    unsigned r = 0;
    r = __builtin_amdgcn_cvt_pk_fp8_f32(a, b, r, false);  // bytes 0-1
    r = __builtin_amdgcn_cvt_pk_fp8_f32(c, d, r, true);   // bytes 2-3
    return r;
}

__device__ __forceinline__ void gload_lds16(const void* g, void* l) {
    __builtin_amdgcn_global_load_lds(
        (const __attribute__((address_space(1))) void*)g,
        (__attribute__((address_space(3))) void*)l, 16, 0, 0);
}

// Permuted fp8 layout (r10, verified absmax=0): within each 128-B k-tile,
// byte c holds element k(c) = ((c>>4)&3)*32 + ((c>>6)&1)*16 + (c&15), so
// the conflict-free r8 read columns (hi*16, 64+hi*16 ^ row swizzle) deliver
// the v8i32 K=128 fragment directly. For 8-aligned c the 8 bytes are the
// consecutive input elements starting at kb(c).

// ---------------- fp32 -> fp8 conversion (embeddings, permuted) -----------
__global__ __launch_bounds__(256) void convE8_k(const float* __restrict__ in,
                                                unsigned char* __restrict__ out,
                                                size_t nchunks) {
    size_t i = (size_t)blockIdx.x * 256 + threadIdx.x;
    if (i >= nchunks) return;
    size_t o = i * 8;
    unsigned c = (unsigned)o & 127;
    unsigned kb = ((c >> 4) & 3) * 32 + ((c >> 6) & 1) * 16 + (c & 8);
    const float* src = in + (o & ~(size_t)127) + kb;
    float4 a = *(const float4*)src;
    float4 b = *(const float4*)(src + 4);
    uint2 v = { cvt8x4(a.x, a.y, a.z, a.w), cvt8x4(b.x, b.y, b.z, b.w) };
    *(uint2*)(out + o) = v;
}

// ---------------- fp32 -> fp8 conversion (weight, permuted, zero-pad) -----
__global__ __launch_bounds__(256) void convW8_k(const float* __restrict__ wt,
                                                unsigned char* __restrict__ out,
                                                int V, size_t nchunks) {
    for (size_t i = (size_t)blockIdx.x * 256 + threadIdx.x; i < nchunks;
         i += (size_t)gridDim.x * 256) {
        size_t o = i * 8;
        size_t v = o >> 11;
        uint2 val = {0u, 0u};
        if (v < (size_t)V) {
            unsigned c = (unsigned)o & 127;
            unsigned kb = ((c >> 4) & 3) * 32 + ((c >> 6) & 1) * 16 + (c & 8);
            const float* src = wt + (o & ~(size_t)127) + kb;
            float4 a = *(const float4*)src;
            float4 b = *(const float4*)(src + 4);
            val = (uint2){ cvt8x4(a.x, a.y, a.z, a.w), cvt8x4(b.x, b.y, b.z, b.w) };
        }
        *(uint2*)(out + o) = val;
    }
}

// ---------------- 256x256 MX-fp8 GEMM, merged 4-region schedule -----------
// r10 had 8 barriers per 2 K-tiles; measured residual ~300 cyc/region of
// barrier skew. This merges region pairs: 4 regions/iter, each =
// {barrier; 2 stage calls (first, for HBM slack); 16 MFMA; ds_reads for a
// LATER region}. Register shape IDENTICAL to r10 (c1 is re-read AFTER its
// last MFMA use in the same region — WAR on the register enforces order,
// no new live range; r5/r6/r7 showed any added pressure spills at the
// 256-reg unified cap).
//
// Merged ledger (iter i; at M0 entry: buf0=T(2i) landed, buf1.B=T(2i+1).B
// landed, aX=buf0.A mh0, bP=buf0.B nh0, c1=buf0.B nh1 in regs):
//  M0: stage buf1.A.h0,h1(2i+1) | MFMA T2i (0,0)aX,bP (0,1)aX,c1 | read aY<-buf0.A mh1 | WAITV(0)
//  M1: stage buf0.B.h0,h1(2i+2) | MFMA T2i (1,1)aY,c1 (1,0)aY,bP | read aX<-buf1.A mh0, bQ<-buf1.B nh0, c1<-buf1.B nh1
//  M2: stage buf0.A.h0,h1(2i+2) | MFMA T2i+1 (0,0)aX,bQ (0,1)aX,c1 | read aY<-buf1.A mh1 | WAITV(0)
//  M3: stage buf1.B.h0,h1(2i+3) | MFMA T2i+1 (1,1)aY,c1 (1,0)aY,bQ | read aX<-buf0.A mh0, bP<-buf0.B nh0, c1<-buf0.B nh1
// WAITV(0)@M0-end: drains prev-M3 buf1.B (issued ~2800 cyc ago) + M0 buf1.A
//   (issued at M0 start, ~2600 cyc slack vs ~900 HBM latency) -> buf1 fully
//   landed+published (next barrier) for M1/M2 reads. Symmetric @M2-end for
//   buf0. Stage write-after-read (all 4 checked): target buffer's last
//   ds_read is >=1 barrier before the stage issues. Tail wrap (kt&15)
//   re-stages tile 0/1 into buffers whose subsequent reads are dead ✓.

#define LDAF(DST, B, MH)                                                    \
    do {                                                                    \
        _Pragma("unroll") for (int mm = 0; mm < 4; ++mm) {                  \
            i32x4 u = *(const i32x4*)(smem + offA[B][0] + (MH)*8192 +       \
                                      mm * 2048);                           \
            i32x4 w = *(const i32x4*)(smem + offA[B][1] + (MH)*8192 +       \
                                      mm * 2048);                           \
            DST[mm] = __builtin_shufflevector(u, w, 0, 1, 2, 3, 4, 5, 6, 7);\
        }                                                                   \
    } while (0)
#define LDBF(DST, B, NH)                                                    \
    do {                                                                    \
        _Pragma("unroll") for (int nn = 0; nn < 2; ++nn) {                  \
            i32x4 u = *(const i32x4*)(smem + offB[B][0] + (NH)*4096 +       \
                                      nn * 2048);                           \
            i32x4 w = *(const i32x4*)(smem + offB[B][1] + (NH)*4096 +       \
                                      nn * 2048);                           \
            DST[nn] = __builtin_shufflevector(u, w, 0, 1, 2, 3, 4, 5, 6, 7);\
        }                                                                   \
    } while (0)
// unit scales: e8m0 exponent 127 -> 2^0 = 1.0
#define MFMAQ(MH, NH, AARR, BARR)                                           \
    do {                                                                    \
        __builtin_amdgcn_s_setprio(1);                                      \
        _Pragma("unroll") for (int mm = 0; mm < 4; ++mm)                    \
        _Pragma("unroll") for (int nn = 0; nn < 2; ++nn)                    \
            acc[(MH)*4 + mm][(NH)*2 + nn] =                                 \
                __builtin_amdgcn_mfma_scale_f32_16x16x128_f8f6f4(           \
                    AARR[mm], BARR[nn], acc[(MH)*4 + mm][(NH)*2 + nn],      \
                    0, 0, 0, 0x7F7F7F7F, 0, 0x7F7F7F7F);                    \
        __builtin_amdgcn_s_setprio(0);                                      \
    } while (0)
#define RBAR()                                                              \
    do {                                                                    \
        __builtin_amdgcn_s_barrier();                                       \
        __builtin_amdgcn_sched_barrier(0);                                  \
    } while (0)
#define WAITV(N) asm volatile("s_waitcnt vmcnt(" #N ")" ::: "memory")

__global__ __launch_bounds__(THREADS, 2) void gemm_lse256_k(
    const unsigned char* __restrict__ E8,    // [4096][2048 B] permuted fp8
    const unsigned char* __restrict__ W8,    // [Vpad][2048 B] permuted fp8
    const float* __restrict__ bias,          // [V]
    float2* __restrict__ partials,           // [NR][NVT]
    int NVT, int V) {
    extern __shared__ char smem[];
    const int t = threadIdx.x;
    const int lane = t & 63;
    const int wave = t >> 6;
    const int wr = wave >> 2;   // 0..1
    const int wc = wave & 3;    // 0..3
    const int lo = lane & 15;
    const int hi = lane >> 4;

    // bijective XCD swizzle (m204)
    const int nwg = NMT * NVT;
    const int xcd = blockIdx.x & 7;
    const int idx = blockIdx.x >> 3;
    const int q8 = nwg >> 3, r8 = nwg & 7;
    const int swz = (xcd < r8 ? xcd * (q8 + 1) : r8 * (q8 + 1) + (xcd - r8) * q8) + idx;
    const int mt = swz & (NMT - 1);
    const int vt = swz >> 4;

    const unsigned char* Ag = E8 + (size_t)mt * BM * DD;
    const unsigned char* Bg = W8 + (size_t)vt * BN * DD;

    f32x4 acc[8][4];
#pragma unroll
    for (int m = 0; m < 8; ++m)
#pragma unroll
        for (int n = 0; n < 4; ++n) acc[m][n] = (f32x4){0.f, 0.f, 0.f, 0.f};
    i32x8 aX[4], aY[4], bP[2], bQ[2], c1[2];

    // ---- precomputed LDS read base offsets (r8's conflict-free columns) ----
    const int xorm = (lo & 7) << 4;
    int cbx[2];
    cbx[0] = (hi * 16) ^ xorm;
    cbx[1] = (64 + hi * 16) ^ xorm;
    int offA[2][2], offB[2][2];  // [buf][half] byte offsets into smem
#pragma unroll
    for (int b = 0; b < 2; ++b)
#pragma unroll
        for (int k = 0; k < 2; ++k) {
            offA[b][k] = b * 65536 + (wr * 128 + lo) * 128 + cbx[k];
            offB[b][k] = 32768 + b * 65536 + (wc * 64 + lo) * 128 + cbx[k];
        }

    // ---- precomputed stage pointers (loop-invariant) ----
    const int srow = lane >> 3;
    const int cbs = ((lane & 7) * 16) ^ (srow << 4);
    const unsigned char* gA[2][2];  // [j][h]
    const unsigned char* gB[2][2];
#pragma unroll
    for (int j = 0; j < 2; ++j)
#pragma unroll
        for (int h = 0; h < 2; ++h) {
            int row = (wave * 2 + j) * 8 + srow;
            gA[j][h] = Ag + (size_t)(h * 128 + row) * DD + cbs;
            gB[j][h] = Bg + (size_t)(h * 128 + row) * DD + cbs;
        }
    const int wbyte = wave * 2048;

    auto stageA = [&](int b, int h, int kt) {
        int ktc = (kt & (NKT - 1)) * BKB;
#pragma unroll
        for (int j = 0; j < 2; ++j)
            gload_lds16(gA[j][h] + ktc,
                        smem + b * 65536 + h * 16384 + wbyte + j * 1024);
    };
    auto stageB = [&](int b, int h, int kt) {
        int ktc = (kt & (NKT - 1)) * BKB;
#pragma unroll
        for (int j = 0; j < 2; ++j)
            gload_lds16(gB[j][h] + ktc,
                        smem + 32768 + b * 65536 + h * 16384 + wbyte + j * 1024);
    };

    // prologue: T0 -> buf0 (4 halves), T1.B -> buf1 (2 halves)
    stageA(0, 0, 0); stageA(0, 1, 0);
    stageB(0, 0, 0); stageB(0, 1, 0);
    stageB(1, 0, 1); stageB(1, 1, 1);
    WAITV(4);   // T0 landed; T1.B (4 loads) in flight
    __builtin_amdgcn_s_barrier();
    __builtin_amdgcn_sched_barrier(0);
    // pre-load M0's operands from buf0
    LDAF(aX, 0, 0);
    LDBF(bP, 0, 0);
    LDBF(c1, 0, 1);

    for (int i = 0; i < NKT / 2; ++i) {
        const int k1 = 2 * i + 1, k2 = 2 * i + 2, k3 = 2 * i + 3;
        // M0
        RBAR();
        stageA(1, 0, k1); stageA(1, 1, k1);
        MFMAQ(0, 0, aX, bP);
        MFMAQ(0, 1, aX, c1);
        LDAF(aY, 0, 1);
        WAITV(0);
        // M1
        RBAR();
        stageB(0, 0, k2); stageB(0, 1, k2);
        MFMAQ(1, 1, aY, c1);
        MFMAQ(1, 0, aY, bP);
        LDAF(aX, 1, 0);
        LDBF(bQ, 1, 0);
        LDBF(c1, 1, 1);   // WAR: after c1's last use above
        // M2
        RBAR();
        stageA(0, 0, k2); stageA(0, 1, k2);
        MFMAQ(0, 0, aX, bQ);
        MFMAQ(0, 1, aX, c1);
        LDAF(aY, 1, 1);
        WAITV(0);
        // M3
        RBAR();
        stageB(1, 0, k3); stageB(1, 1, k3);
        MFMAQ(1, 1, aY, c1);
        MFMAQ(1, 0, aY, bQ);
        LDAF(aX, 0, 0);
        LDBF(bP, 0, 0);
        LDBF(c1, 0, 1);   // WAR: after c1's last use above
    }

    WAITV(0);
    __syncthreads();

    // ---- epilogue: bias add + per-row (max, sumexp) over this 256-col tile
    float* redM = (float*)(smem + 131072);
    float* redS = (float*)(smem + 135168);
    const int colbase = vt * BN + wc * 64 + lo;
    float bias_n[4];
#pragma unroll
    for (int n = 0; n < 4; ++n) {
        int col = colbase + n * 16;
        bias_n[n] = (col < V) ? bias[col] : 0.0f;
    }
#pragma unroll
    for (int m = 0; m < 8; ++m) {
#pragma unroll
        for (int qq = 0; qq < 4; ++qq) {
            float l[4];
            float vmax = -1e30f;
#pragma unroll
            for (int n = 0; n < 4; ++n) {
                int col = colbase + n * 16;
                float x = (col < V) ? (acc[m][n][qq] + bias_n[n]) : -1e30f;
                l[n] = x;
                vmax = fmaxf(vmax, x);
            }
#pragma unroll
            for (int d = 1; d < 16; d <<= 1) vmax = fmaxf(vmax, __shfl_xor(vmax, d));
            float s = 0.f;
#pragma unroll
            for (int n = 0; n < 4; ++n) s += __expf(l[n] - vmax);
#pragma unroll
            for (int d = 1; d < 16; d <<= 1) s += __shfl_xor(s, d);
            if (lo == 0) {
                int R = wr * 128 + m * 16 + hi * 4 + qq;
                redM[wc * 256 + R] = vmax;
                redS[wc * 256 + R] = s;
            }
        }
    }
    __syncthreads();
    if (t < 256) {
        float M = redM[t], S = redS[t];
#pragma unroll
        for (int w2 = 1; w2 < 4; ++w2) {
            float m2 = redM[w2 * 256 + t], s2 = redS[w2 * 256 + t];
            float nM = fmaxf(M, m2);
            S = S * __expf(M - nM) + s2 * __expf(m2 - nM);
            M = nM;
        }
        size_t row = (size_t)mt * BM + t;
        partials[row * (size_t)NVT + vt] = make_float2(M, S);
    }
}

// ---------------- fp32 true-logit per row (one wave per row) --------------
__global__ __launch_bounds__(256) void true_logit_k(
    const float* __restrict__ emb, const float* __restrict__ wt,
    const float* __restrict__ bias, const int* __restrict__ labels,
    float* __restrict__ tl, int* __restrict__ validf, int NR, int V, int S) {
    int wid = blockIdx.x * 4 + (threadIdx.x >> 6);
    int lane = threadIdx.x & 63;
    if (wid >= NR) return;
    int b = wid / S, s = wid % S;
    int valid = 0;
    float val = 0.f;
    if (s < S - 1) {
        int y = labels[b * S + s + 1];
        if (y != IGNORE_INDEX) {
            valid = 1;
            int ys = (y >= 0 && y < V) ? y : 0;
            const float4* e4 = (const float4*)(emb + ((size_t)b * S + s) * DD);
            const float4* w4 = (const float4*)(wt + (size_t)ys * DD);
            float sum = 0.f;
            for (int i = lane; i < DD / 4; i += 64) {
                float4 aa = e4[i], w = w4[i];
                sum += aa.x * w.x + aa.y * w.y + aa.z * w.z + aa.w * w.w;
            }
#pragma unroll
            for (int d = 1; d < 64; d <<= 1) sum += __shfl_xor(sum, d);
            val = sum + bias[ys];
        }
    }
    if (lane == 0) {
        tl[wid] = val;
        validf[wid] = valid;
    }
}

// ---------------- combine partials -> per-row NLL -> global sum -----------
__global__ __launch_bounds__(256) void reduce_rows_k(
    const float2* __restrict__ partials, const float* __restrict__ tl,
    const int* __restrict__ validf, float* __restrict__ accum, int NR,
    int NVT, int S) {
    int wid = blockIdx.x * 4 + (threadIdx.x >> 6);
    int lane = threadIdx.x & 63;
    if (wid >= NR) return;
    int s = wid % S;
    if (s >= S - 1) return;
    if (!validf[wid]) return;
    float M = -1e30f, Sm = 0.f;
    const float2* p = partials + (size_t)wid * NVT;
    for (int v = lane; v < NVT; v += 64) {
        float2 ms = p[v];
        float nM = fmaxf(M, ms.x);
        Sm = Sm * __expf(M - nM) + ms.y * __expf(ms.x - nM);
        M = nM;
    }
#pragma unroll
    for (int d = 1; d < 64; d <<= 1) {
        float oM = __shfl_xor(M, d), oS = __shfl_xor(Sm, d);
        float nM = fmaxf(M, oM);
        Sm = Sm * __expf(M - nM) + oS * __expf(oM - nM);
        M = nM;
    }
    if (lane == 0) {
        float lse = M + __logf(Sm);
        float nll = lse - tl[wid];
        atomicAdd(&accum[0], nll);
        atomicAdd(&accum[1], 1.0f);
    }
}

__global__ void finalize_k(const float* __restrict__ accum,
                           float* __restrict__ out) {
    out[0] = accum[0] / fmaxf(accum[1], 1.0f);
}

extern "C" void kernel_launch(void* const* d_in, const int* in_sizes, int n_in,
                              void* d_out, int out_size, void* d_ws,
                              size_t ws_size, hipStream_t stream) {
    const float* emb = (const float*)d_in[0];
    const float* wt = (const float*)d_in[1];
    const float* bias = (const float*)d_in[2];
    const int* labels = (const int*)d_in[3];

    const int B = 2, S = 2048;
    const int V = in_sizes[2];            // 50257
    const int NR = B * S;                 // 4096
    const int NVT = (V + BN - 1) / BN;    // 197
    const int Vpad = NVT * BN;            // 50432

    char* p = (char*)d_ws;
    unsigned char* E8 = (unsigned char*)p;
    p += (size_t)NR * DD;
    float2* partials = (float2*)p;
    p += (size_t)NR * NVT * sizeof(float2);
    float* tl = (float*)p;
    p += (size_t)NR * 4;
    int* validf = (int*)p;
    p += (size_t)NR * 4;
    float* accum = (float*)p;
    p += 256;
    unsigned char* W8 = (unsigned char*)p;

    hipMemsetAsync(accum, 0, 8, stream);

    size_t echunks = (size_t)NR * DD / 8;
    convE8_k<<<(int)((echunks + 255) / 256), 256, 0, stream>>>(emb, E8, echunks);

    size_t wchunks = (size_t)Vpad * DD / 8;
    convW8_k<<<8192, 256, 0, stream>>>(wt, W8, V, wchunks);

    hipFuncSetAttribute((const void*)gemm_lse256_k,
                        hipFuncAttributeMaxDynamicSharedMemorySize, LDS_TOTAL);
    gemm_lse256_k<<<NMT * NVT, THREADS, LDS_TOTAL, stream>>>(E8, W8, bias,
                                                             partials, NVT, V);

    true_logit_k<<<NR / 4, 256, 0, stream>>>(emb, wt, bias, labels, tl, validf,
                                             NR, V, S);
    reduce_rows_k<<<NR / 4, 256, 0, stream>>>(partials, tl, validf, accum, NR,
                                              NVT, S);
    finalize_k<<<1, 1, 0, stream>>>(accum, (float*)d_out);
}

// Round 12
// 681.116 us; speedup vs baseline: 5.6967x; 1.0065x over previous
//
#include <hip/hip_runtime.h>

#define IGNORE_INDEX (-100)
#define DD 2048
#define BM 256
#define BN 256
#define BKB 128   // K-tile in BYTES = 128 fp8 elements
#define NKT 16    // DD/128
#define NMT 16    // 4096/BM
#define THREADS 512
#define LDS_TOTAL 139264

typedef __attribute__((ext_vector_type(4))) float f32x4;
typedef __attribute__((ext_vector_type(8))) int i32x8;
typedef __attribute__((ext_vector_type(4))) int i32x4;

// ---- fp32 -> fp8 e4m3 (OCP) pair-pack via HW converter -------------------
__device__ __forceinline__ unsigned cvt8x4(float a, float b, float c, float d) {
    unsigned r = 0;
    r = __builtin_amdgcn_cvt_pk_fp8_f32(a, b, r, false);  // bytes 0-1
    r = __builtin_amdgcn_cvt_pk_fp8_f32(c, d, r, true);   // bytes 2-3
    return r;
}

__device__ __forceinline__ void gload_lds16(const void* g, void* l) {
    __builtin_amdgcn_global_load_lds(
        (const __attribute__((address_space(1))) void*)g,
        (__attribute__((address_space(3))) void*)l, 16, 0, 0);
}

// Permuted fp8 layout (r10, verified absmax=0): within each 128-B k-tile,
// byte c holds element k(c) = ((c>>4)&3)*32 + ((c>>6)&1)*16 + (c&15), so
// the conflict-free r8 read columns (hi*16, 64+hi*16 ^ row swizzle) deliver
// the v8i32 K=128 fragment directly. For 8-aligned c the 8 bytes are the
// consecutive input elements starting at kb(c).

// ---------------- fp32 -> fp8 conversion (embeddings, permuted) -----------
__global__ __launch_bounds__(256) void convE8_k(const float* __restrict__ in,
                                                unsigned char* __restrict__ out,
                                                size_t nchunks) {
    size_t i = (size_t)blockIdx.x * 256 + threadIdx.x;
    if (i >= nchunks) return;
    size_t o = i * 8;
    unsigned c = (unsigned)o & 127;
    unsigned kb = ((c >> 4) & 3) * 32 + ((c >> 6) & 1) * 16 + (c & 8);
    const float* src = in + (o & ~(size_t)127) + kb;
    float4 a = *(const float4*)src;
    float4 b = *(const float4*)(src + 4);
    uint2 v = { cvt8x4(a.x, a.y, a.z, a.w), cvt8x4(b.x, b.y, b.z, b.w) };
    *(uint2*)(out + o) = v;
}

// ---------------- fp32 -> fp8 conversion (weight, permuted, zero-pad) -----
__global__ __launch_bounds__(256) void convW8_k(const float* __restrict__ wt,
                                                unsigned char* __restrict__ out,
                                                int V, size_t nchunks) {
    for (size_t i = (size_t)blockIdx.x * 256 + threadIdx.x; i < nchunks;
         i += (size_t)gridDim.x * 256) {
        size_t o = i * 8;
        size_t v = o >> 11;
        uint2 val = {0u, 0u};
        if (v < (size_t)V) {
            unsigned c = (unsigned)o & 127;
            unsigned kb = ((c >> 4) & 3) * 32 + ((c >> 6) & 1) * 16 + (c & 8);
            const float* src = wt + (o & ~(size_t)127) + kb;
            float4 a = *(const float4*)src;
            float4 b = *(const float4*)(src + 4);
            val = (uint2){ cvt8x4(a.x, a.y, a.z, a.w), cvt8x4(b.x, b.y, b.z, b.w) };
        }
        *(uint2*)(out + o) = val;
    }
}

// ---------------- 256x256 MX-fp8 GEMM, merged 4-region schedule -----------
// r11's merged schedule, WITHOUT the per-barrier sched_barrier(0) compiler
// fences. r11 measured region = 3158 cyc = MFMA 1106 + LDS ~1400 + ~650:
// pipes serialized by issue order, and the sched_barrier fences forbade the
// compiler from interleaving next-region ds_reads under the MFMA cluster.
// Safety without fences: MFMA<->read ordering is register data-dep;
// ds_read<->gload_lds ordering is LDS alias-conservatism (both directions);
// fresh-data reads can't hoist above WAITV (asm memory clobber); cross-wave
// WAR distances are >=2 runtime barriers (ledger below). The scheduler may
// only move provably-safe ops — the overlap we failed to force by hand
// (r5 SGB: spill; r6 branch: spill; r7 reorder: spill) it can now do with
// regalloc awareness.
//
// Merged ledger (iter i; at M0 entry: buf0=T(2i) landed, buf1.B=T(2i+1).B
// landed, aX=buf0.A mh0, bP=buf0.B nh0, c1=buf0.B nh1 in regs):
//  M0: stage buf1.A.h0,h1(2i+1) | MFMA T2i (0,0)aX,bP (0,1)aX,c1 | read aY<-buf0.A mh1 | WAITV(0)
//  M1: stage buf0.B.h0,h1(2i+2) | MFMA T2i (1,1)aY,c1 (1,0)aY,bP | read aX<-buf1.A, bQ,c1<-buf1.B
//  M2: stage buf0.A.h0,h1(2i+2) | MFMA T2i+1 (0,0)aX,bQ (0,1)aX,c1 | read aY<-buf1.A mh1 | WAITV(0)
//  M3: stage buf1.B.h0,h1(2i+3) | MFMA T2i+1 (1,1)aY,c1 (1,0)aY,bQ | read aX,bP,c1<-buf0
// WAITV(0)@M0-end drains buf1 (prev-M3's B + M0's A) before the M0->M1
// barrier publishes for M1/M2 reads; symmetric @M2-end for buf0. Stage
// write-after-read: target buffer's last ds_read >=1 barrier earlier (all
// 4 regions checked). Tail wrap (kt&15) re-stages dead-read buffers ✓.

#define LDAF(DST, B, MH)                                                    \
    do {                                                                    \
        _Pragma("unroll") for (int mm = 0; mm < 4; ++mm) {                  \
            i32x4 u = *(const i32x4*)(smem + offA[B][0] + (MH)*8192 +       \
                                      mm * 2048);                           \
            i32x4 w = *(const i32x4*)(smem + offA[B][1] + (MH)*8192 +       \
                                      mm * 2048);                           \
            DST[mm] = __builtin_shufflevector(u, w, 0, 1, 2, 3, 4, 5, 6, 7);\
        }                                                                   \
    } while (0)
#define LDBF(DST, B, NH)                                                    \
    do {                                                                    \
        _Pragma("unroll") for (int nn = 0; nn < 2; ++nn) {                  \
            i32x4 u = *(const i32x4*)(smem + offB[B][0] + (NH)*4096 +       \
                                      nn * 2048);                           \
            i32x4 w = *(const i32x4*)(smem + offB[B][1] + (NH)*4096 +       \
                                      nn * 2048);                           \
            DST[nn] = __builtin_shufflevector(u, w, 0, 1, 2, 3, 4, 5, 6, 7);\
        }                                                                   \
    } while (0)
// unit scales: e8m0 exponent 127 -> 2^0 = 1.0
#define MFMAQ(MH, NH, AARR, BARR)                                           \
    do {                                                                    \
        __builtin_amdgcn_s_setprio(1);                                      \
        _Pragma("unroll") for (int mm = 0; mm < 4; ++mm)                    \
        _Pragma("unroll") for (int nn = 0; nn < 2; ++nn)                    \
            acc[(MH)*4 + mm][(NH)*2 + nn] =                                 \
                __builtin_amdgcn_mfma_scale_f32_16x16x128_f8f6f4(           \
                    AARR[mm], BARR[nn], acc[(MH)*4 + mm][(NH)*2 + nn],      \
                    0, 0, 0, 0x7F7F7F7F, 0, 0x7F7F7F7F);                    \
        __builtin_amdgcn_s_setprio(0);                                      \
    } while (0)
#define RBAR() __builtin_amdgcn_s_barrier()
#define WAITV(N) asm volatile("s_waitcnt vmcnt(" #N ")" ::: "memory")

__global__ __launch_bounds__(THREADS, 2) void gemm_lse256_k(
    const unsigned char* __restrict__ E8,    // [4096][2048 B] permuted fp8
    const unsigned char* __restrict__ W8,    // [Vpad][2048 B] permuted fp8
    const float* __restrict__ bias,          // [V]
    float2* __restrict__ partials,           // [NR][NVT]
    int NVT, int V) {
    extern __shared__ char smem[];
    const int t = threadIdx.x;
    const int lane = t & 63;
    const int wave = t >> 6;
    const int wr = wave >> 2;   // 0..1
    const int wc = wave & 3;    // 0..3
    const int lo = lane & 15;
    const int hi = lane >> 4;

    // bijective XCD swizzle (m204)
    const int nwg = NMT * NVT;
    const int xcd = blockIdx.x & 7;
    const int idx = blockIdx.x >> 3;
    const int q8 = nwg >> 3, r8 = nwg & 7;
    const int swz = (xcd < r8 ? xcd * (q8 + 1) : r8 * (q8 + 1) + (xcd - r8) * q8) + idx;
    const int mt = swz & (NMT - 1);
    const int vt = swz >> 4;

    const unsigned char* Ag = E8 + (size_t)mt * BM * DD;
    const unsigned char* Bg = W8 + (size_t)vt * BN * DD;

    f32x4 acc[8][4];
#pragma unroll
    for (int m = 0; m < 8; ++m)
#pragma unroll
        for (int n = 0; n < 4; ++n) acc[m][n] = (f32x4){0.f, 0.f, 0.f, 0.f};
    i32x8 aX[4], aY[4], bP[2], bQ[2], c1[2];

    // ---- precomputed LDS read base offsets (r8's conflict-free columns) ----
    const int xorm = (lo & 7) << 4;
    int cbx[2];
    cbx[0] = (hi * 16) ^ xorm;
    cbx[1] = (64 + hi * 16) ^ xorm;
    int offA[2][2], offB[2][2];  // [buf][half] byte offsets into smem
#pragma unroll
    for (int b = 0; b < 2; ++b)
#pragma unroll
        for (int k = 0; k < 2; ++k) {
            offA[b][k] = b * 65536 + (wr * 128 + lo) * 128 + cbx[k];
            offB[b][k] = 32768 + b * 65536 + (wc * 64 + lo) * 128 + cbx[k];
        }

    // ---- precomputed stage pointers (loop-invariant) ----
    const int srow = lane >> 3;
    const int cbs = ((lane & 7) * 16) ^ (srow << 4);
    const unsigned char* gA[2][2];  // [j][h]
    const unsigned char* gB[2][2];
#pragma unroll
    for (int j = 0; j < 2; ++j)
#pragma unroll
        for (int h = 0; h < 2; ++h) {
            int row = (wave * 2 + j) * 8 + srow;
            gA[j][h] = Ag + (size_t)(h * 128 + row) * DD + cbs;
            gB[j][h] = Bg + (size_t)(h * 128 + row) * DD + cbs;
        }
    const int wbyte = wave * 2048;

    auto stageA = [&](int b, int h, int kt) {
        int ktc = (kt & (NKT - 1)) * BKB;
#pragma unroll
        for (int j = 0; j < 2; ++j)
            gload_lds16(gA[j][h] + ktc,
                        smem + b * 65536 + h * 16384 + wbyte + j * 1024);
    };
    auto stageB = [&](int b, int h, int kt) {
        int ktc = (kt & (NKT - 1)) * BKB;
#pragma unroll
        for (int j = 0; j < 2; ++j)
            gload_lds16(gB[j][h] + ktc,
                        smem + 32768 + b * 65536 + h * 16384 + wbyte + j * 1024);
    };

    // prologue: T0 -> buf0 (4 halves), T1.B -> buf1 (2 halves)
    stageA(0, 0, 0); stageA(0, 1, 0);
    stageB(0, 0, 0); stageB(0, 1, 0);
    stageB(1, 0, 1); stageB(1, 1, 1);
    WAITV(4);   // T0 landed; T1.B (4 loads) in flight
    __builtin_amdgcn_s_barrier();
    // pre-load M0's operands from buf0
    LDAF(aX, 0, 0);
    LDBF(bP, 0, 0);
    LDBF(c1, 0, 1);

    for (int i = 0; i < NKT / 2; ++i) {
        const int k1 = 2 * i + 1, k2 = 2 * i + 2, k3 = 2 * i + 3;
        // M0
        RBAR();
        stageA(1, 0, k1); stageA(1, 1, k1);
        MFMAQ(0, 0, aX, bP);
        MFMAQ(0, 1, aX, c1);
        LDAF(aY, 0, 1);
        WAITV(0);
        // M1
        RBAR();
        stageB(0, 0, k2); stageB(0, 1, k2);
        MFMAQ(1, 1, aY, c1);
        MFMAQ(1, 0, aY, bP);
        LDAF(aX, 1, 0);
        LDBF(bQ, 1, 0);
        LDBF(c1, 1, 1);   // WAR: after c1's last use above
        // M2
        RBAR();
        stageA(0, 0, k2); stageA(0, 1, k2);
        MFMAQ(0, 0, aX, bQ);
        MFMAQ(0, 1, aX, c1);
        LDAF(aY, 1, 1);
        WAITV(0);
        // M3
        RBAR();
        stageB(1, 0, k3); stageB(1, 1, k3);
        MFMAQ(1, 1, aY, c1);
        MFMAQ(1, 0, aY, bQ);
        LDAF(aX, 0, 0);
        LDBF(bP, 0, 0);
        LDBF(c1, 0, 1);   // WAR: after c1's last use above
    }

    WAITV(0);
    __syncthreads();

    // ---- epilogue: bias add + per-row (max, sumexp) over this 256-col tile
    float* redM = (float*)(smem + 131072);
    float* redS = (float*)(smem + 135168);
    const int colbase = vt * BN + wc * 64 + lo;
    float bias_n[4];
#pragma unroll
    for (int n = 0; n < 4; ++n) {
        int col = colbase + n * 16;
        bias_n[n] = (col < V) ? bias[col] : 0.0f;
    }
#pragma unroll
    for (int m = 0; m < 8; ++m) {
#pragma unroll
        for (int qq = 0; qq < 4; ++qq) {
            float l[4];
            float vmax = -1e30f;
#pragma unroll
            for (int n = 0; n < 4; ++n) {
                int col = colbase + n * 16;
                float x = (col < V) ? (acc[m][n][qq] + bias_n[n]) : -1e30f;
                l[n] = x;
                vmax = fmaxf(vmax, x);
            }
#pragma unroll
            for (int d = 1; d < 16; d <<= 1) vmax = fmaxf(vmax, __shfl_xor(vmax, d));
            float s = 0.f;
#pragma unroll
            for (int n = 0; n < 4; ++n) s += __expf(l[n] - vmax);
#pragma unroll
            for (int d = 1; d < 16; d <<= 1) s += __shfl_xor(s, d);
            if (lo == 0) {
                int R = wr * 128 + m * 16 + hi * 4 + qq;
                redM[wc * 256 + R] = vmax;
                redS[wc * 256 + R] = s;
            }
        }
    }
    __syncthreads();
    if (t < 256) {
        float M = redM[t], S = redS[t];
#pragma unroll
        for (int w2 = 1; w2 < 4; ++w2) {
            float m2 = redM[w2 * 256 + t], s2 = redS[w2 * 256 + t];
            float nM = fmaxf(M, m2);
            S = S * __expf(M - nM) + s2 * __expf(m2 - nM);
            M = nM;
        }
        size_t row = (size_t)mt * BM + t;
        partials[row * (size_t)NVT + vt] = make_float2(M, S);
    }
}

// ---------------- fp32 true-logit per row (one wave per row) --------------
__global__ __launch_bounds__(256) void true_logit_k(
    const float* __restrict__ emb, const float* __restrict__ wt,
    const float* __restrict__ bias, const int* __restrict__ labels,
    float* __restrict__ tl, int* __restrict__ validf, int NR, int V, int S) {
    int wid = blockIdx.x * 4 + (threadIdx.x >> 6);
    int lane = threadIdx.x & 63;
    if (wid >= NR) return;
    int b = wid / S, s = wid % S;
    int valid = 0;
    float val = 0.f;
    if (s < S - 1) {
        int y = labels[b * S + s + 1];
        if (y != IGNORE_INDEX) {
            valid = 1;
            int ys = (y >= 0 && y < V) ? y : 0;
            const float4* e4 = (const float4*)(emb + ((size_t)b * S + s) * DD);
            const float4* w4 = (const float4*)(wt + (size_t)ys * DD);
            float sum = 0.f;
            for (int i = lane; i < DD / 4; i += 64) {
                float4 aa = e4[i], w = w4[i];
                sum += aa.x * w.x + aa.y * w.y + aa.z * w.z + aa.w * w.w;
            }
#pragma unroll
            for (int d = 1; d < 64; d <<= 1) sum += __shfl_xor(sum, d);
            val = sum + bias[ys];
        }
    }
    if (lane == 0) {
        tl[wid] = val;
        validf[wid] = valid;
    }
}

// ---------------- combine partials -> per-row NLL -> global sum -----------
__global__ __launch_bounds__(256) void reduce_rows_k(
    const float2* __restrict__ partials, const float* __restrict__ tl,
    const int* __restrict__ validf, float* __restrict__ accum, int NR,
    int NVT, int S) {
    int wid = blockIdx.x * 4 + (threadIdx.x >> 6);
    int lane = threadIdx.x & 63;
    if (wid >= NR) return;
    int s = wid % S;
    if (s >= S - 1) return;
    if (!validf[wid]) return;
    float M = -1e30f, Sm = 0.f;
    const float2* p = partials + (size_t)wid * NVT;
    for (int v = lane; v < NVT; v += 64) {
        float2 ms = p[v];
        float nM = fmaxf(M, ms.x);
        Sm = Sm * __expf(M - nM) + ms.y * __expf(ms.x - nM);
        M = nM;
    }
#pragma unroll
    for (int d = 1; d < 64; d <<= 1) {
        float oM = __shfl_xor(M, d), oS = __shfl_xor(Sm, d);
        float nM = fmaxf(M, oM);
        Sm = Sm * __expf(M - nM) + oS * __expf(oM - nM);
        M = nM;
    }
    if (lane == 0) {
        float lse = M + __logf(Sm);
        float nll = lse - tl[wid];
        atomicAdd(&accum[0], nll);
        atomicAdd(&accum[1], 1.0f);
    }
}

__global__ void finalize_k(const float* __restrict__ accum,
                           float* __restrict__ out) {
    out[0] = accum[0] / fmaxf(accum[1], 1.0f);
}

extern "C" void kernel_launch(void* const* d_in, const int* in_sizes, int n_in,
                              void* d_out, int out_size, void* d_ws,
                              size_t ws_size, hipStream_t stream) {
    const float* emb = (const float*)d_in[0];
    const float* wt = (const float*)d_in[1];
    const float* bias = (const float*)d_in[2];
    const int* labels = (const int*)d_in[3];

    const int B = 2, S = 2048;
    const int V = in_sizes[2];            // 50257
    const int NR = B * S;                 // 4096
    const int NVT = (V + BN - 1) / BN;    // 197
    const int Vpad = NVT * BN;            // 50432

    char* p = (char*)d_ws;
    unsigned char* E8 = (unsigned char*)p;
    p += (size_t)NR * DD;
    float2* partials = (float2*)p;
    p += (size_t)NR * NVT * sizeof(float2);
    float* tl = (float*)p;
    p += (size_t)NR * 4;
    int* validf = (int*)p;
    p += (size_t)NR * 4;
    float* accum = (float*)p;
    p += 256;
    unsigned char* W8 = (unsigned char*)p;

    hipMemsetAsync(accum, 0, 8, stream);

    size_t echunks = (size_t)NR * DD / 8;
    convE8_k<<<(int)((echunks + 255) / 256), 256, 0, stream>>>(emb, E8, echunks);

    size_t wchunks = (size_t)Vpad * DD / 8;
    convW8_k<<<8192, 256, 0, stream>>>(wt, W8, V, wchunks);

    hipFuncSetAttribute((const void*)gemm_lse256_k,
                        hipFuncAttributeMaxDynamicSharedMemorySize, LDS_TOTAL);
    gemm_lse256_k<<<NMT * NVT, THREADS, LDS_TOTAL, stream>>>(E8, W8, bias,
                                                             partials, NVT, V);

    true_logit_k<<<NR / 4, 256, 0, stream>>>(emb, wt, bias, labels, tl, validf,
                                             NR, V, S);
    reduce_rows_k<<<NR / 4, 256, 0, stream>>>(partials, tl, validf, accum, NR,
                                              NVT, S);
    finalize_k<<<1, 1, 0, stream>>>(accum, (float*)d_out);
}